// Round 6
// baseline (314.987 us; speedup 1.0000x reference)
//
#include <hip/hip_runtime.h>
#include <math.h>

#define B_  4
#define L_  8192
#define D_  512
#define BL_ (B_*L_)
#define TOK 64
#define XS  68            // 64 tok + 2 halo + 2 pad
#define KC  16
#define NCH (D_/KC)

// ---------------------------------------------------------------------------
// Signal + e. R1 geometry (165us baseline) minus LDS instructions:
//  - wsp (pf weights) now live in registers: prefetched 8x float4 per chunk
//    from global (L2-resident), snapshotted before next LOAD. Saves 8 b128
//    reads + 1 write per thread per chunk.
//  - conv handles 4 tokens/thread (t<128): per row 1 b128 + 2 b32 vs
//    2x(b64+2b32); pf stored as 1 b128. Bit-identical tap order per token.
// LDS model: 10.8K -> ~9.2K cyc/CU/chunk (LDS-bound), predict ~148us.
// ---------------------------------------------------------------------------
__global__ __launch_bounds__(256, 2) void k_signal(
    const float* __restrict__ x, const float* __restrict__ mask,
    const float* __restrict__ W1, const float* __restrict__ b1,
    const float* __restrict__ W2, const float* __restrict__ b2,
    const float* __restrict__ Wc, const float* __restrict__ bc,
    const float* __restrict__ Wb1, const float* __restrict__ bb1,
    const float* __restrict__ Wb2, const float* __restrict__ bb2,
    float* __restrict__ signal, float* __restrict__ e)
{
  __shared__ float ws1[KC][128];   // W1 chunk rows kc..kc+15
  __shared__ float wsb[KC][128];   // Wb1 x-part chunk
  __shared__ float xt[KC][XS];     // x transposed; col 64 = l0-1, 65 = l0+64
  __shared__ float pf[8][XS];      // conv out chunk

  const int t   = threadIdx.x;
  const int blk = blockIdx.x;          // 512 = 4 b x 128 tiles
  const int b   = blk >> 7;
  const int l0  = (blk & 127) << 6;
  const float* xb = x + (size_t)b * L_ * D_;

  const int jq = t & 31, tw = t >> 5;
  const int j0 = jq << 2, tok0 = tw << 3;

  // x-staging / e role: all 256 threads, one float4 per chunk
  const int stok = t >> 2, skk = t & 3;
  // conv role (t<128): out-ch oo_c, 4 tokens tokq..tokq+3
  const int oo_c = (t >> 4) & 7;
  const int tokq = (t & 15) << 2;
  const int cb_c = (oo_c >> 1) << 2;   // rel in-channel base {0,4,8,12}

  const int srow = t >> 5, sc4 = (t & 31) << 2;

  float a1[8][4], a2[8][4];
#pragma unroll
  for (int i = 0; i < 8; ++i)
#pragma unroll
    for (int j = 0; j < 4; ++j) { a1[i][j] = 0.f; a2[i][j] = 0.f; }
  float esacc = 0.f;

  // prefetch registers (next chunk)
  float4 r_w1a, r_w1b, r_wba, r_wbb, r_xv, r_hv;
  float4 r_wp[8];                  // pf weights, cols j0..j0+3 for oo 0..7
  float4 r_wc0, r_wc1, r_wc2;
  float  r_bc;

  auto LOAD = [&](int c) {
    const int kc = c << 4;
    r_w1a = *reinterpret_cast<const float4*>(W1  + (size_t)(kc + srow) * 128 + sc4);
    r_w1b = *reinterpret_cast<const float4*>(W1  + (size_t)(kc + 8 + srow) * 128 + sc4);
    r_wba = *reinterpret_cast<const float4*>(Wb1 + (size_t)(kc + srow) * 128 + sc4);
    r_wbb = *reinterpret_cast<const float4*>(Wb1 + (size_t)(kc + 8 + srow) * 128 + sc4);
    {
      const float* wpg = Wb1 + (size_t)(512 + (c << 3)) * 128 + j0;
#pragma unroll
      for (int oo = 0; oo < 8; ++oo)
        r_wp[oo] = *reinterpret_cast<const float4*>(wpg + (oo << 7));
    }
    r_xv  = *reinterpret_cast<const float4*>(xb + (size_t)(l0 + stok) * D_ + kc + (skk << 2));
    if (t < 8) {
      const int hh = t >> 2, kk = t & 3;
      const int l = hh ? (l0 + TOK) : (l0 - 1);
      r_hv = make_float4(0.f, 0.f, 0.f, 0.f);
      if (l >= 0 && l < L_)
        r_hv = *reinterpret_cast<const float4*>(xb + (size_t)l * D_ + kc + (kk << 2));
    }
    const int o = (c << 3) + oo_c;
    const float* wcp = Wc + o * 12;
    r_wc0 = *reinterpret_cast<const float4*>(wcp);
    r_wc1 = *reinterpret_cast<const float4*>(wcp + 4);
    r_wc2 = *reinterpret_cast<const float4*>(wcp + 8);
    r_bc  = bc[o];
  };

  LOAD(0);

  for (int c = 0; c < NCH; ++c) {
    __syncthreads();                   // previous chunk fully consumed

    // ---- write staged registers into LDS ----
    *reinterpret_cast<float4*>(&ws1[srow][sc4])     = r_w1a;
    *reinterpret_cast<float4*>(&ws1[8 + srow][sc4]) = r_w1b;
    *reinterpret_cast<float4*>(&wsb[srow][sc4])     = r_wba;
    *reinterpret_cast<float4*>(&wsb[8 + srow][sc4]) = r_wbb;
    {
      const float4 v = r_xv;
      esacc = fmaf(v.x, v.x, esacc); esacc = fmaf(v.y, v.y, esacc);
      esacc = fmaf(v.z, v.z, esacc); esacc = fmaf(v.w, v.w, esacc);
      const int r = skk << 2;
      xt[r + 0][stok] = v.x; xt[r + 1][stok] = v.y;
      xt[r + 2][stok] = v.z; xt[r + 3][stok] = v.w;
    }
    if (t < 8) {
      const int hh = t >> 2, kk = t & 3;
      const int col = TOK + hh, r = kk << 2;
      xt[r + 0][col] = r_hv.x; xt[r + 1][col] = r_hv.y;
      xt[r + 2][col] = r_hv.z; xt[r + 3][col] = r_hv.w;
    }
    __syncthreads();                   // staged data visible

    // snapshot this chunk's reg-resident weights before prefetch overwrites
    float wcl[12];
    wcl[0] = r_wc0.x; wcl[1]  = r_wc0.y; wcl[2]  = r_wc0.z; wcl[3]  = r_wc0.w;
    wcl[4] = r_wc1.x; wcl[5]  = r_wc1.y; wcl[6]  = r_wc1.z; wcl[7]  = r_wc1.w;
    wcl[8] = r_wc2.x; wcl[9]  = r_wc2.y; wcl[10] = r_wc2.z; wcl[11] = r_wc2.w;
    const float bcv = r_bc;
    float4 wpl[8];
#pragma unroll
    for (int oo = 0; oo < 8; ++oo) wpl[oo] = r_wp[oo];

    if (c + 1 < NCH) LOAD(c + 1);      // issue next chunk's global loads

    // ---- conv: out-ch (c*8+oo_c), tokens tokq..tokq+3 (t<128) ----
    if (t < 128) {
      float p0 = bcv, p1 = bcv, p2 = bcv, p3 = bcv;
#pragma unroll
      for (int i = 0; i < 4; ++i) {
        const float* row = &xt[cb_c + i][0];
        const float  xm1 = (tokq == 0) ? row[TOK] : row[tokq - 1];
        const float4 x4  = *reinterpret_cast<const float4*>(&row[tokq]);
        const float  xp4 = (tokq == 60) ? row[TOK + 1] : row[tokq + 4];
        const float w0 = wcl[i * 3 + 0], w1 = wcl[i * 3 + 1], w2 = wcl[i * 3 + 2];
        p0 = fmaf(xm1,  w0, p0); p0 = fmaf(x4.x, w1, p0); p0 = fmaf(x4.y, w2, p0);
        p1 = fmaf(x4.x, w0, p1); p1 = fmaf(x4.y, w1, p1); p1 = fmaf(x4.z, w2, p1);
        p2 = fmaf(x4.y, w0, p2); p2 = fmaf(x4.z, w1, p2); p2 = fmaf(x4.w, w2, p2);
        p3 = fmaf(x4.z, w0, p3); p3 = fmaf(x4.w, w1, p3); p3 = fmaf(xp4,  w2, p3);
      }
      *reinterpret_cast<float4*>(&pf[oo_c][tokq]) = make_float4(p0, p1, p2, p3);
    }

    // ---- GEMM x-part: 4 b128 -> 64 FMA per k ----
#pragma unroll 4
    for (int k = 0; k < KC; ++k) {
      const float4 w1 = *reinterpret_cast<const float4*>(&ws1[k][j0]);
      const float4 wb = *reinterpret_cast<const float4*>(&wsb[k][j0]);
      const float4 xa = *reinterpret_cast<const float4*>(&xt[k][tok0]);
      const float4 xc = *reinterpret_cast<const float4*>(&xt[k][tok0 + 4]);
      const float xs8[8] = {xa.x, xa.y, xa.z, xa.w, xc.x, xc.y, xc.z, xc.w};
#pragma unroll
      for (int i = 0; i < 8; ++i) {
        a1[i][0] = fmaf(xs8[i], w1.x, a1[i][0]);
        a1[i][1] = fmaf(xs8[i], w1.y, a1[i][1]);
        a1[i][2] = fmaf(xs8[i], w1.z, a1[i][2]);
        a1[i][3] = fmaf(xs8[i], w1.w, a1[i][3]);
        a2[i][0] = fmaf(xs8[i], wb.x, a2[i][0]);
        a2[i][1] = fmaf(xs8[i], wb.y, a2[i][1]);
        a2[i][2] = fmaf(xs8[i], wb.z, a2[i][2]);
        a2[i][3] = fmaf(xs8[i], wb.w, a2[i][3]);
      }
    }
    __syncthreads();                   // pf writes visible

    // ---- GEMM pf-part: weights from registers (wpl), pf from LDS ----
#pragma unroll
    for (int oo = 0; oo < 8; ++oo) {
      const float4 wp = wpl[oo];
      const float4 pa4 = *reinterpret_cast<const float4*>(&pf[oo][tok0]);
      const float4 pb4 = *reinterpret_cast<const float4*>(&pf[oo][tok0 + 4]);
      const float ps8[8] = {pa4.x, pa4.y, pa4.z, pa4.w, pb4.x, pb4.y, pb4.z, pb4.w};
#pragma unroll
      for (int i = 0; i < 8; ++i) {
        a2[i][0] = fmaf(ps8[i], wp.x, a2[i][0]);
        a2[i][1] = fmaf(ps8[i], wp.y, a2[i][1]);
        a2[i][2] = fmaf(ps8[i], wp.z, a2[i][2]);
        a2[i][3] = fmaf(ps8[i], wp.w, a2[i][3]);
      }
    }
  }

  // ---- epilogue: relu, project, cross-jq reduce, sigmoid ----
  {
    float b1v[4], w2v[4], bbv[4], wv2[4];
#pragma unroll
    for (int jj = 0; jj < 4; ++jj) {
      b1v[jj] = b1[j0 + jj];  w2v[jj] = W2[j0 + jj];
      bbv[jj] = bb1[j0 + jj]; wv2[jj] = Wb2[j0 + jj];
    }
    const float bias2 = b2[0], biasb2 = bb2[0];
#pragma unroll
    for (int i = 0; i < 8; ++i) {
      float p1 = 0.f, p2 = 0.f;
#pragma unroll
      for (int jj = 0; jj < 4; ++jj) {
        const float h1 = a1[i][jj] + b1v[jj];
        if (h1 > 0.f) p1 = fmaf(h1, w2v[jj], p1);
        const float h2 = a2[i][jj] + bbv[jj];
        if (h2 > 0.f) p2 = fmaf(h2, wv2[jj], p2);
      }
#pragma unroll
      for (int off = 1; off < 32; off <<= 1) {
        p1 += __shfl_xor(p1, off, 64);
        p2 += __shfl_xor(p2, off, 64);
      }
      if (jq == 0) {
        const int gi = b * L_ + l0 + tok0 + i;
        const float content = 1.f / (1.f + expf(-(p1 + bias2)));
        const float bscore  = 1.f / (1.f + expf(-(p2 + biasb2)));
        signal[gi] = content * (1.f - bscore) * mask[gi];
      }
    }
  }

  // ---- e epilogue: reduce over the 4 skk lanes of each token ----
  {
    float es = esacc;
    es += __shfl_xor(es, 1, 64);
    es += __shfl_xor(es, 2, 64);
    if (skk == 0) {
      const int gi = b * L_ + l0 + stok;
      const float m = mask[gi];
      e[gi] = m * m * es;
    }
  }
}

// ---------------------------------------------------------------------------
// Fused quantile + enforce. One block (1024 thr) per batch row.
// bounds-write moved to k_merge; 256-entry prefix now wave-parallel.
// ---------------------------------------------------------------------------
__device__ __forceinline__ int chain_sim(unsigned long long w, int from) {
  int last = -1;
  while (from < 64) {
    const unsigned long long m = w & (~0ull << from);
    if (m == 0ull) break;
    const int p = __ffsll(m) - 1;
    last = p;
    from = p + 4;
  }
  return last;
}

__global__ __launch_bounds__(1024) void k_select(
    const float* __restrict__ signal,
    int* __restrict__ starts, int* __restrict__ nlast)
{
  __shared__ unsigned int bins[4][256];
  __shared__ unsigned int sel_prefix;
  __shared__ int sel_rank;
  __shared__ float sh_thr;
  __shared__ unsigned int wmin[16];
  __shared__ int wcnt[16];
  __shared__ unsigned long long cw[128];
  __shared__ unsigned char nb[L_];
  __shared__ signed char tbl[128][4];
  __shared__ int st_in[128];
  __shared__ int offs[257];

  const int b = blockIdx.x, t = threadIdx.x;
  const int wv = t >> 6, lane = t & 63;
  const float* s = signal + b * L_;

  float val[8];
  unsigned int key[8];
#pragma unroll
  for (int i = 0; i < 8; ++i) {
    val[i] = s[(i << 10) + t];
    const unsigned int u = __float_as_uint(val[i]);
    key[i] = (u & 0x80000000u) ? ~u : (u | 0x80000000u);
  }

  // ---- radix select rank 5733 = floor(0.7*(L-1)) ----
  if (t == 0) { sel_prefix = 0u; sel_rank = 5733; }
  __syncthreads();
  for (int round = 0; round < 4; ++round) {
    reinterpret_cast<unsigned int*>(bins)[t] = 0u;
    __syncthreads();
    const unsigned int pre = sel_prefix;
    const int shift = 24 - 8 * round;
#pragma unroll
    for (int i = 0; i < 8; ++i) {
      if (round == 0 || (key[i] >> (shift + 8)) == pre)
        atomicAdd(&bins[t >> 8][(key[i] >> shift) & 255u], 1u);
    }
    __syncthreads();
    if (t < 256)
      bins[0][t] = bins[0][t] + bins[1][t] + bins[2][t] + bins[3][t];
    __syncthreads();
    if (t < 64) {
      const unsigned int c0 = bins[0][(t << 2) + 0], c1 = bins[0][(t << 2) + 1];
      const unsigned int c2 = bins[0][(t << 2) + 2], c3 = bins[0][(t << 2) + 3];
      const unsigned int lsum = c0 + c1 + c2 + c3;
      unsigned int run = lsum;
#pragma unroll
      for (int off = 1; off < 64; off <<= 1) {
        const unsigned int v = __shfl_up(run, off, 64);
        if (t >= off) run += v;
      }
      const int r = sel_rank;
      if (r >= (int)(run - lsum) && r < (int)run) {
        int rr = r - (int)(run - lsum);
        unsigned int cbin;
        if (rr < (int)c0) { cbin = 0; }
        else if (rr < (int)(c0 + c1)) { cbin = 1; rr -= (int)c0; }
        else if (rr < (int)(c0 + c1 + c2)) { cbin = 2; rr -= (int)(c0 + c1); }
        else { cbin = 3; rr -= (int)(c0 + c1 + c2); }
        sel_rank = rr;
        sel_prefix = (pre << 8) | ((unsigned int)(t << 2) | cbin);
      }
    }
    __syncthreads();
  }
  const unsigned int k0 = sel_prefix;

  // ---- successor: count <=k0 and min of keys > k0 (tie-safe) ----
  {
    int cle = 0;
    unsigned int mgt = 0xFFFFFFFFu;
#pragma unroll
    for (int i = 0; i < 8; ++i) {
      if (key[i] <= k0) ++cle;
      else mgt = min(mgt, key[i]);
    }
#pragma unroll
    for (int off = 1; off < 64; off <<= 1) {
      cle += __shfl_xor(cle, off, 64);
      mgt = min(mgt, (unsigned int)__shfl_xor((int)mgt, off, 64));
    }
    if (lane == 0) { wcnt[wv] = cle; wmin[wv] = mgt; }
    __syncthreads();
    if (t == 0) {
      int C = 0; unsigned int M = 0xFFFFFFFFu;
      for (int g = 0; g < 16; ++g) { C += wcnt[g]; M = min(M, wmin[g]); }
      const unsigned int k1 = (C >= 5735) ? k0 : M;
      const unsigned int u0 = (k0 & 0x80000000u) ? (k0 & 0x7fffffffu) : ~k0;
      const unsigned int u1 = (k1 & 0x80000000u) ? (k1 & 0x7fffffffu) : ~k1;
      const float v0 = __uint_as_float(u0);
      const float v1 = __uint_as_float(u1);
      const float g = 0.7f * 8191.0f - 5733.0f;
      sh_thr = v0 + g * (v1 - v0);
    }
    __syncthreads();
  }
  const float thr = sh_thr;

  // ---- candidate bitmap from register values ----
#pragma unroll
  for (int i = 0; i < 8; ++i) {
    const unsigned long long m = __ballot(val[i] < thr);
    if (lane == 0) cw[(i << 4) + wv] = m;
  }
  {
    const int base = t << 3;
#pragma unroll
    for (int i = 0; i < 8; ++i) nb[base + i] = 0;
  }
  __syncthreads();
  if (t == 0) cw[127] |= (1ull << 63);   // forced candidate at L-1
  __syncthreads();

  // ---- (1) per-64-block transition tables ----
  if (t < 512) {
    const int blk = t >> 2, cls = t & 3;
    tbl[blk][cls] = (signed char)chain_sim(cw[blk], cls);
  }
  __syncthreads();

  // ---- (2) serial 128-step state scan ----
  if (t == 0) {
    int st = 0;
    for (int blk = 0; blk < 128; ++blk) {
      const int bs = blk << 6;
      st_in[blk] = st;
      int pl;
      if (blk == 0) {
        pl = chain_sim(cw[0], 4);
      } else {
        int off = st + 4 - bs;
        if (off < 0) off = 0;
        pl = tbl[blk][off];
      }
      if (pl >= 0) st = bs + pl;
    }
  }
  __syncthreads();

  // ---- (3) parallel emission of acceptance + split bytes ----
  if (t < 128) {
    const int bs = t << 6;
    const unsigned long long w = cw[t];
    int st = st_in[t];
    int from = st + 4 - bs;
    if (from < 0) from = 0;
    while (from < 64) {
      const unsigned long long m = w & (~0ull << from);
      if (m == 0ull) break;
      const int p_rel = __ffsll(m) - 1;
      const int p = bs + p_rel;
      nb[p] = 1;
      const int ps = p - st;
      const int k = (ps + 15) >> 4;
      if (k > 1) {
        int sz = ps / k; if (sz < 1) sz = 1;
        for (int j = 1; j < k; ++j) nb[st + j * sz] = 1;
      }
      st = p;
      from = p_rel + 4;
    }
  }
  __syncthreads();

  // ---- wave-parallel prefix scan over 256 x 32-token sums ----
  int ls = 0, run = 0;
  if (t < 256) {
    const int base = t << 5;
    for (int i = 0; i < 32; ++i) ls += nb[base + i];
    run = ls;
#pragma unroll
    for (int off = 1; off < 64; off <<= 1) {
      const int v = __shfl_up(run, off, 64);
      if ((t & 63) >= off) run += v;
    }
    if ((t & 63) == 63) wcnt[t >> 6] = run;   // reuse wcnt as wave partials
  }
  __syncthreads();
  if (t < 256) {
    const int w = t >> 6;
    int addb = 0;
    if (w > 0) addb += wcnt[0];
    if (w > 1) addb += wcnt[1];
    if (w > 2) addb += wcnt[2];
    offs[t] = addb + run - ls;                // exclusive prefix
    if (t == 255) offs[256] = addb + run;
  }
  __syncthreads();
  if (t < 256) {
    const int base = t << 5;
    int rn = offs[t];
    for (int i = 0; i < 32; ++i) {
      rn += nb[base + i];
      if (nb[base + i]) starts[b * L_ + rn] = base + i;
    }
  }
  if (t == 0) { starts[b * L_ + 0] = 0; nlast[b] = offs[256]; }
}

// ---------------------------------------------------------------------------
// Segment softmax-merge (R5 v2) + bounds write (moved from k_select).
// ---------------------------------------------------------------------------
__global__ __launch_bounds__(256) void k_merge(const float* __restrict__ x,
    const float* __restrict__ mask, const float* __restrict__ e,
    const int* __restrict__ starts, const int* __restrict__ nlast,
    float* __restrict__ merged, float* __restrict__ bounds)
{
  const int idx = (blockIdx.x << 2) + (threadIdx.x >> 6);
  const int b   = idx >> 13;
  const int sid = idx & (L_ - 1);
  const int n = nlast[b];
  const int lane = threadIdx.x & 63;
  if (lane == 0)
    bounds[(size_t)b * L_ + sid] = (sid >= 1 && sid <= n) ? 1.0f : 0.0f;
  const int c0 = lane << 3;
  float* o = merged + (size_t)(b * L_ + sid) * D_ + c0;
  if (sid > n) {
    const float4 z = make_float4(0.f, 0.f, 0.f, 0.f);
    reinterpret_cast<float4*>(o)[0] = z;
    reinterpret_cast<float4*>(o)[1] = z;
    return;
  }
  const int t0 = starts[b * L_ + sid];
  const int t1 = (sid < n) ? starts[b * L_ + sid + 1] : L_;
  const int len = t1 - t0;
  const float* eb = e + b * L_;

  float acc[8] = {0,0,0,0,0,0,0,0};

  if (len <= 64) {
    // ---- whole segment in-wave: 1 coalesced e load + shfl reductions ----
    const float ev = (lane < len) ? eb[t0 + lane] : -INFINITY;
    float mx = ev;
#pragma unroll
    for (int off = 1; off < 64; off <<= 1)
      mx = fmaxf(mx, __shfl_xor(mx, off, 64));
    const float ex = expf(ev - mx);          // 0 for dead lanes
    float den = ex;
#pragma unroll
    for (int off = 1; off < 64; off <<= 1)
      den += __shfl_xor(den, off, 64);
    const float mk = (lane < len) ? mask[b * L_ + t0 + lane] : 0.f;
    const float scl = (ex / den) * mk;       // per-lane: weight of row t0+lane

    // ---- x-row loop with 2-deep load pipeline ----
    const float* xr = x + (size_t)(b * L_ + t0) * D_ + c0;
    float4 u0 = reinterpret_cast<const float4*>(xr)[0];
    float4 u1 = reinterpret_cast<const float4*>(xr)[1];
    for (int r = 0; r < len; ++r) {
      float4 n0, n1;
      if (r + 1 < len) {
        const float* xn = xr + (size_t)(r + 1) * D_;
        n0 = reinterpret_cast<const float4*>(xn)[0];
        n1 = reinterpret_cast<const float4*>(xn)[1];
      }
      const float sc = __shfl(scl, r, 64);
      acc[0] = fmaf(sc, u0.x, acc[0]); acc[1] = fmaf(sc, u0.y, acc[1]);
      acc[2] = fmaf(sc, u0.z, acc[2]); acc[3] = fmaf(sc, u0.w, acc[3]);
      acc[4] = fmaf(sc, u1.x, acc[4]); acc[5] = fmaf(sc, u1.y, acc[5]);
      acc[6] = fmaf(sc, u1.z, acc[6]); acc[7] = fmaf(sc, u1.w, acc[7]);
      u0 = n0; u1 = n1;
    }
  } else {
    // ---- fallback (len > 64): original serial path ----
    float mx = -INFINITY;
    for (int p = t0; p < t1; ++p) mx = fmaxf(mx, eb[p]);
    float den = 0.f;
    for (int p = t0; p < t1; ++p) den += expf(eb[p] - mx);
    for (int p = t0; p < t1; ++p) {
      const float wn = expf(eb[p] - mx) / den;
      const float sc = wn * mask[b * L_ + p];
      const float* xr = x + ((size_t)(b * L_ + p)) * D_ + c0;
      const float4 u0 = reinterpret_cast<const float4*>(xr)[0];
      const float4 u1 = reinterpret_cast<const float4*>(xr)[1];
      acc[0] = fmaf(sc, u0.x, acc[0]); acc[1] = fmaf(sc, u0.y, acc[1]);
      acc[2] = fmaf(sc, u0.z, acc[2]); acc[3] = fmaf(sc, u0.w, acc[3]);
      acc[4] = fmaf(sc, u1.x, acc[4]); acc[5] = fmaf(sc, u1.y, acc[5]);
      acc[6] = fmaf(sc, u1.z, acc[6]); acc[7] = fmaf(sc, u1.w, acc[7]);
    }
  }
  reinterpret_cast<float4*>(o)[0] = make_float4(acc[0], acc[1], acc[2], acc[3]);
  reinterpret_cast<float4*>(o)[1] = make_float4(acc[4], acc[5], acc[6], acc[7]);
}

// ---------------------------------------------------------------------------
extern "C" void kernel_launch(void* const* d_in, const int* in_sizes, int n_in,
                              void* d_out, int out_size, void* d_ws, size_t ws_size,
                              hipStream_t stream) {
  (void)in_sizes; (void)n_in; (void)out_size; (void)ws_size;
  const float* x    = (const float*)d_in[0];
  const float* mask = (const float*)d_in[1];
  const float* W1   = (const float*)d_in[2];
  const float* b1   = (const float*)d_in[3];
  const float* W2   = (const float*)d_in[4];
  const float* b2   = (const float*)d_in[5];
  const float* Wc   = (const float*)d_in[6];
  const float* bc   = (const float*)d_in[7];
  const float* Wb1  = (const float*)d_in[8];
  const float* bb1  = (const float*)d_in[9];
  const float* Wb2  = (const float*)d_in[10];
  const float* bb2  = (const float*)d_in[11];

  float* merged = (float*)d_out;
  float* bounds = (float*)d_out + (size_t)BL_ * D_;

  char* ws = (char*)d_ws;
  float* signal = (float*)(ws);
  float* e      = (float*)(ws + (size_t)BL_ * 4);
  int*   starts = (int*)  (ws + (size_t)BL_ * 8);
  int*   nlast  = (int*)  (ws + (size_t)BL_ * 12);

  k_signal<<<BL_ / TOK, 256, 0, stream>>>(x, mask, W1, b1, W2, b2, Wc, bc,
                                          Wb1, bb1, Wb2, bb2, signal, e);
  k_select<<<B_, 1024, 0, stream>>>(signal, starts, nlast);
  k_merge<<<BL_ / 4, 256, 0, stream>>>(x, mask, e, starts, nlast, merged, bounds);
}

// Round 7
// 301.518 us; speedup vs baseline: 1.0447x; 1.0447x over previous
//
#include <hip/hip_runtime.h>
#include <math.h>

#define B_  4
#define L_  8192
#define D_  512
#define BL_ (B_*L_)
#define TOK 64
#define XS  68            // 64 tok + 2 halo + 2 pad
#define KC  16
#define NCH (D_/KC)

// ---------------------------------------------------------------------------
// Signal + e — exact R1/R5 kernel (best measured: 165-167 us, VGPR 84).
// TOK=64/block (512 blocks, 2/CU), T=8 tok x J=4 j per thread; weights via
// LDS; register prefetch of next chunk. R6's wsp->reg variant cost +44 VGPR
// and regressed (182 us) — reverted. This geometry is a verified sharp local
// optimum: R0/R2/R3/R4/R6 perturbations all measured slower.
// ---------------------------------------------------------------------------
__global__ __launch_bounds__(256, 2) void k_signal(
    const float* __restrict__ x, const float* __restrict__ mask,
    const float* __restrict__ W1, const float* __restrict__ b1,
    const float* __restrict__ W2, const float* __restrict__ b2,
    const float* __restrict__ Wc, const float* __restrict__ bc,
    const float* __restrict__ Wb1, const float* __restrict__ bb1,
    const float* __restrict__ Wb2, const float* __restrict__ bb2,
    float* __restrict__ signal, float* __restrict__ e)
{
  __shared__ float ws1[KC][128];   // W1 chunk rows kc..kc+15
  __shared__ float wsb[KC][128];   // Wb1 x-part chunk
  __shared__ float wsp[8][128];    // Wb1 pf-part chunk (8 conv channels/chunk)
  __shared__ float xt[KC][XS];     // x transposed; col 64 = l0-1, 65 = l0+64
  __shared__ float pf[8][XS];      // conv out chunk

  const int t   = threadIdx.x;
  const int blk = blockIdx.x;          // 512 = 4 b x 128 tiles
  const int b   = blk >> 7;
  const int l0  = (blk & 127) << 6;
  const float* xb = x + (size_t)b * L_ * D_;

  const int jq = t & 31, tw = t >> 5;
  const int j0 = jq << 2, tok0 = tw << 3;

  // x-staging / e role: all 256 threads, one float4 per chunk
  const int stok = t >> 2, skk = t & 3;
  // conv role: out-ch oo_c, adjacent token pair (m2, m2+1)
  const int oo_c = t >> 5;             // 0..7
  const int m2   = (t & 31) << 1;      // 0,2,...,62
  const int cb_c = (oo_c >> 1) << 2;   // rel in-channel base {0,4,8,12}

  const int srow = t >> 5, sc4 = (t & 31) << 2;

  float a1[8][4], a2[8][4];
#pragma unroll
  for (int i = 0; i < 8; ++i)
#pragma unroll
    for (int j = 0; j < 4; ++j) { a1[i][j] = 0.f; a2[i][j] = 0.f; }
  float esacc = 0.f;

  // prefetch registers (next chunk)
  float4 r_w1a, r_w1b, r_wba, r_wbb, r_wp, r_xv, r_hv;
  float4 r_wc0, r_wc1, r_wc2;
  float  r_bc;

  auto LOAD = [&](int c) {
    const int kc = c << 4;
    r_w1a = *reinterpret_cast<const float4*>(W1  + (size_t)(kc + srow) * 128 + sc4);
    r_w1b = *reinterpret_cast<const float4*>(W1  + (size_t)(kc + 8 + srow) * 128 + sc4);
    r_wba = *reinterpret_cast<const float4*>(Wb1 + (size_t)(kc + srow) * 128 + sc4);
    r_wbb = *reinterpret_cast<const float4*>(Wb1 + (size_t)(kc + 8 + srow) * 128 + sc4);
    r_wp  = *reinterpret_cast<const float4*>(Wb1 + (size_t)(512 + (c << 3) + srow) * 128 + sc4);
    r_xv  = *reinterpret_cast<const float4*>(xb + (size_t)(l0 + stok) * D_ + kc + (skk << 2));
    if (t < 8) {
      const int hh = t >> 2, kk = t & 3;
      const int l = hh ? (l0 + TOK) : (l0 - 1);
      r_hv = make_float4(0.f, 0.f, 0.f, 0.f);
      if (l >= 0 && l < L_)
        r_hv = *reinterpret_cast<const float4*>(xb + (size_t)l * D_ + kc + (kk << 2));
    }
    const int o = (c << 3) + oo_c;
    const float* wcp = Wc + o * 12;
    r_wc0 = *reinterpret_cast<const float4*>(wcp);
    r_wc1 = *reinterpret_cast<const float4*>(wcp + 4);
    r_wc2 = *reinterpret_cast<const float4*>(wcp + 8);
    r_bc  = bc[o];
  };

  LOAD(0);

  for (int c = 0; c < NCH; ++c) {
    __syncthreads();                   // previous chunk fully consumed

    // ---- write staged registers into LDS ----
    *reinterpret_cast<float4*>(&ws1[srow][sc4])     = r_w1a;
    *reinterpret_cast<float4*>(&ws1[8 + srow][sc4]) = r_w1b;
    *reinterpret_cast<float4*>(&wsb[srow][sc4])     = r_wba;
    *reinterpret_cast<float4*>(&wsb[8 + srow][sc4]) = r_wbb;
    *reinterpret_cast<float4*>(&wsp[srow][sc4])     = r_wp;
    {
      const float4 v = r_xv;
      esacc = fmaf(v.x, v.x, esacc); esacc = fmaf(v.y, v.y, esacc);
      esacc = fmaf(v.z, v.z, esacc); esacc = fmaf(v.w, v.w, esacc);
      const int r = skk << 2;
      xt[r + 0][stok] = v.x; xt[r + 1][stok] = v.y;
      xt[r + 2][stok] = v.z; xt[r + 3][stok] = v.w;
    }
    if (t < 8) {
      const int hh = t >> 2, kk = t & 3;
      const int col = TOK + hh, r = kk << 2;
      xt[r + 0][col] = r_hv.x; xt[r + 1][col] = r_hv.y;
      xt[r + 2][col] = r_hv.z; xt[r + 3][col] = r_hv.w;
    }
    __syncthreads();                   // staged data visible

    // keep this chunk's conv weights before the prefetch overwrites them
    float wcl[12];
    wcl[0] = r_wc0.x; wcl[1]  = r_wc0.y; wcl[2]  = r_wc0.z; wcl[3]  = r_wc0.w;
    wcl[4] = r_wc1.x; wcl[5]  = r_wc1.y; wcl[6]  = r_wc1.z; wcl[7]  = r_wc1.w;
    wcl[8] = r_wc2.x; wcl[9]  = r_wc2.y; wcl[10] = r_wc2.z; wcl[11] = r_wc2.w;
    const float bcv = r_bc;

    if (c + 1 < NCH) LOAD(c + 1);      // issue next chunk's global loads

    // ---- conv: out-ch (c*8+oo_c), tokens m2 and m2+1 ----
    {
      float pa = bcv, pb = bcv;
      const int tm1 = (m2 == 0) ? TOK : m2 - 1;
      const int tp2 = (m2 + 2 == TOK) ? TOK + 1 : m2 + 2;
#pragma unroll
      for (int i = 0; i < 4; ++i) {
        const float* row = &xt[cb_c + i][0];
        const float  xm1 = row[tm1];
        const float2 x01 = *reinterpret_cast<const float2*>(&row[m2]);
        const float  xp2 = row[tp2];
        pa = fmaf(xm1,   wcl[i * 3 + 0], pa);
        pa = fmaf(x01.x, wcl[i * 3 + 1], pa);
        pa = fmaf(x01.y, wcl[i * 3 + 2], pa);
        pb = fmaf(x01.x, wcl[i * 3 + 0], pb);
        pb = fmaf(x01.y, wcl[i * 3 + 1], pb);
        pb = fmaf(xp2,   wcl[i * 3 + 2], pb);
      }
      *reinterpret_cast<float2*>(&pf[oo_c][m2]) = make_float2(pa, pb);
    }

    // ---- GEMM x-part: 4 b128 -> 64 FMA per k ----
#pragma unroll 4
    for (int k = 0; k < KC; ++k) {
      const float4 w1 = *reinterpret_cast<const float4*>(&ws1[k][j0]);
      const float4 wb = *reinterpret_cast<const float4*>(&wsb[k][j0]);
      const float4 xa = *reinterpret_cast<const float4*>(&xt[k][tok0]);
      const float4 xc = *reinterpret_cast<const float4*>(&xt[k][tok0 + 4]);
      const float xs8[8] = {xa.x, xa.y, xa.z, xa.w, xc.x, xc.y, xc.z, xc.w};
#pragma unroll
      for (int i = 0; i < 8; ++i) {
        a1[i][0] = fmaf(xs8[i], w1.x, a1[i][0]);
        a1[i][1] = fmaf(xs8[i], w1.y, a1[i][1]);
        a1[i][2] = fmaf(xs8[i], w1.z, a1[i][2]);
        a1[i][3] = fmaf(xs8[i], w1.w, a1[i][3]);
        a2[i][0] = fmaf(xs8[i], wb.x, a2[i][0]);
        a2[i][1] = fmaf(xs8[i], wb.y, a2[i][1]);
        a2[i][2] = fmaf(xs8[i], wb.z, a2[i][2]);
        a2[i][3] = fmaf(xs8[i], wb.w, a2[i][3]);
      }
    }
    __syncthreads();                   // pf writes visible

    // ---- GEMM pf-part ----
#pragma unroll 2
    for (int oo = 0; oo < 8; ++oo) {
      const float4 wp = *reinterpret_cast<const float4*>(&wsp[oo][j0]);
      const float4 pa4 = *reinterpret_cast<const float4*>(&pf[oo][tok0]);
      const float4 pb4 = *reinterpret_cast<const float4*>(&pf[oo][tok0 + 4]);
      const float ps8[8] = {pa4.x, pa4.y, pa4.z, pa4.w, pb4.x, pb4.y, pb4.z, pb4.w};
#pragma unroll
      for (int i = 0; i < 8; ++i) {
        a2[i][0] = fmaf(ps8[i], wp.x, a2[i][0]);
        a2[i][1] = fmaf(ps8[i], wp.y, a2[i][1]);
        a2[i][2] = fmaf(ps8[i], wp.z, a2[i][2]);
        a2[i][3] = fmaf(ps8[i], wp.w, a2[i][3]);
      }
    }
  }

  // ---- epilogue: relu, project, cross-jq reduce, sigmoid ----
  {
    float b1v[4], w2v[4], bbv[4], wv2[4];
#pragma unroll
    for (int jj = 0; jj < 4; ++jj) {
      b1v[jj] = b1[j0 + jj];  w2v[jj] = W2[j0 + jj];
      bbv[jj] = bb1[j0 + jj]; wv2[jj] = Wb2[j0 + jj];
    }
    const float bias2 = b2[0], biasb2 = bb2[0];
#pragma unroll
    for (int i = 0; i < 8; ++i) {
      float p1 = 0.f, p2 = 0.f;
#pragma unroll
      for (int jj = 0; jj < 4; ++jj) {
        const float h1 = a1[i][jj] + b1v[jj];
        if (h1 > 0.f) p1 = fmaf(h1, w2v[jj], p1);
        const float h2 = a2[i][jj] + bbv[jj];
        if (h2 > 0.f) p2 = fmaf(h2, wv2[jj], p2);
      }
#pragma unroll
      for (int off = 1; off < 32; off <<= 1) {
        p1 += __shfl_xor(p1, off, 64);
        p2 += __shfl_xor(p2, off, 64);
      }
      if (jq == 0) {
        const int gi = b * L_ + l0 + tok0 + i;
        const float content = 1.f / (1.f + expf(-(p1 + bias2)));
        const float bscore  = 1.f / (1.f + expf(-(p2 + biasb2)));
        signal[gi] = content * (1.f - bscore) * mask[gi];
      }
    }
  }

  // ---- e epilogue: reduce over the 4 skk lanes of each token ----
  {
    float es = esacc;
    es += __shfl_xor(es, 1, 64);
    es += __shfl_xor(es, 2, 64);
    if (skk == 0) {
      const int gi = b * L_ + l0 + stok;
      const float m = mask[gi];
      e[gi] = m * m * es;
    }
  }
}

// ---------------------------------------------------------------------------
// Fused quantile + enforce. One block (1024 thr) per batch row.
// bounds-write moved to k_merge; 256-entry prefix wave-parallel (R6 tail).
// ---------------------------------------------------------------------------
__device__ __forceinline__ int chain_sim(unsigned long long w, int from) {
  int last = -1;
  while (from < 64) {
    const unsigned long long m = w & (~0ull << from);
    if (m == 0ull) break;
    const int p = __ffsll(m) - 1;
    last = p;
    from = p + 4;
  }
  return last;
}

__global__ __launch_bounds__(1024) void k_select(
    const float* __restrict__ signal,
    int* __restrict__ starts, int* __restrict__ nlast)
{
  __shared__ unsigned int bins[4][256];
  __shared__ unsigned int sel_prefix;
  __shared__ int sel_rank;
  __shared__ float sh_thr;
  __shared__ unsigned int wmin[16];
  __shared__ int wcnt[16];
  __shared__ unsigned long long cw[128];
  __shared__ unsigned char nb[L_];
  __shared__ signed char tbl[128][4];
  __shared__ int st_in[128];
  __shared__ int offs[257];

  const int b = blockIdx.x, t = threadIdx.x;
  const int wv = t >> 6, lane = t & 63;
  const float* s = signal + b * L_;

  float val[8];
  unsigned int key[8];
#pragma unroll
  for (int i = 0; i < 8; ++i) {
    val[i] = s[(i << 10) + t];
    const unsigned int u = __float_as_uint(val[i]);
    key[i] = (u & 0x80000000u) ? ~u : (u | 0x80000000u);
  }

  // ---- radix select rank 5733 = floor(0.7*(L-1)) ----
  if (t == 0) { sel_prefix = 0u; sel_rank = 5733; }
  __syncthreads();
  for (int round = 0; round < 4; ++round) {
    reinterpret_cast<unsigned int*>(bins)[t] = 0u;
    __syncthreads();
    const unsigned int pre = sel_prefix;
    const int shift = 24 - 8 * round;
#pragma unroll
    for (int i = 0; i < 8; ++i) {
      if (round == 0 || (key[i] >> (shift + 8)) == pre)
        atomicAdd(&bins[t >> 8][(key[i] >> shift) & 255u], 1u);
    }
    __syncthreads();
    if (t < 256)
      bins[0][t] = bins[0][t] + bins[1][t] + bins[2][t] + bins[3][t];
    __syncthreads();
    if (t < 64) {
      const unsigned int c0 = bins[0][(t << 2) + 0], c1 = bins[0][(t << 2) + 1];
      const unsigned int c2 = bins[0][(t << 2) + 2], c3 = bins[0][(t << 2) + 3];
      const unsigned int lsum = c0 + c1 + c2 + c3;
      unsigned int run = lsum;
#pragma unroll
      for (int off = 1; off < 64; off <<= 1) {
        const unsigned int v = __shfl_up(run, off, 64);
        if (t >= off) run += v;
      }
      const int r = sel_rank;
      if (r >= (int)(run - lsum) && r < (int)run) {
        int rr = r - (int)(run - lsum);
        unsigned int cbin;
        if (rr < (int)c0) { cbin = 0; }
        else if (rr < (int)(c0 + c1)) { cbin = 1; rr -= (int)c0; }
        else if (rr < (int)(c0 + c1 + c2)) { cbin = 2; rr -= (int)(c0 + c1); }
        else { cbin = 3; rr -= (int)(c0 + c1 + c2); }
        sel_rank = rr;
        sel_prefix = (pre << 8) | ((unsigned int)(t << 2) | cbin);
      }
    }
    __syncthreads();
  }
  const unsigned int k0 = sel_prefix;

  // ---- successor: count <=k0 and min of keys > k0 (tie-safe) ----
  {
    int cle = 0;
    unsigned int mgt = 0xFFFFFFFFu;
#pragma unroll
    for (int i = 0; i < 8; ++i) {
      if (key[i] <= k0) ++cle;
      else mgt = min(mgt, key[i]);
    }
#pragma unroll
    for (int off = 1; off < 64; off <<= 1) {
      cle += __shfl_xor(cle, off, 64);
      mgt = min(mgt, (unsigned int)__shfl_xor((int)mgt, off, 64));
    }
    if (lane == 0) { wcnt[wv] = cle; wmin[wv] = mgt; }
    __syncthreads();
    if (t == 0) {
      int C = 0; unsigned int M = 0xFFFFFFFFu;
      for (int g = 0; g < 16; ++g) { C += wcnt[g]; M = min(M, wmin[g]); }
      const unsigned int k1 = (C >= 5735) ? k0 : M;
      const unsigned int u0 = (k0 & 0x80000000u) ? (k0 & 0x7fffffffu) : ~k0;
      const unsigned int u1 = (k1 & 0x80000000u) ? (k1 & 0x7fffffffu) : ~k1;
      const float v0 = __uint_as_float(u0);
      const float v1 = __uint_as_float(u1);
      const float g = 0.7f * 8191.0f - 5733.0f;
      sh_thr = v0 + g * (v1 - v0);
    }
    __syncthreads();
  }
  const float thr = sh_thr;

  // ---- candidate bitmap from register values ----
#pragma unroll
  for (int i = 0; i < 8; ++i) {
    const unsigned long long m = __ballot(val[i] < thr);
    if (lane == 0) cw[(i << 4) + wv] = m;
  }
  {
    const int base = t << 3;
#pragma unroll
    for (int i = 0; i < 8; ++i) nb[base + i] = 0;
  }
  __syncthreads();
  if (t == 0) cw[127] |= (1ull << 63);   // forced candidate at L-1
  __syncthreads();

  // ---- (1) per-64-block transition tables ----
  if (t < 512) {
    const int blk = t >> 2, cls = t & 3;
    tbl[blk][cls] = (signed char)chain_sim(cw[blk], cls);
  }
  __syncthreads();

  // ---- (2) serial 128-step state scan ----
  if (t == 0) {
    int st = 0;
    for (int blk = 0; blk < 128; ++blk) {
      const int bs = blk << 6;
      st_in[blk] = st;
      int pl;
      if (blk == 0) {
        pl = chain_sim(cw[0], 4);
      } else {
        int off = st + 4 - bs;
        if (off < 0) off = 0;
        pl = tbl[blk][off];
      }
      if (pl >= 0) st = bs + pl;
    }
  }
  __syncthreads();

  // ---- (3) parallel emission of acceptance + split bytes ----
  if (t < 128) {
    const int bs = t << 6;
    const unsigned long long w = cw[t];
    int st = st_in[t];
    int from = st + 4 - bs;
    if (from < 0) from = 0;
    while (from < 64) {
      const unsigned long long m = w & (~0ull << from);
      if (m == 0ull) break;
      const int p_rel = __ffsll(m) - 1;
      const int p = bs + p_rel;
      nb[p] = 1;
      const int ps = p - st;
      const int k = (ps + 15) >> 4;
      if (k > 1) {
        int sz = ps / k; if (sz < 1) sz = 1;
        for (int j = 1; j < k; ++j) nb[st + j * sz] = 1;
      }
      st = p;
      from = p_rel + 4;
    }
  }
  __syncthreads();

  // ---- wave-parallel prefix scan over 256 x 32-token sums ----
  int ls = 0, run = 0;
  if (t < 256) {
    const int base = t << 5;
    for (int i = 0; i < 32; ++i) ls += nb[base + i];
    run = ls;
#pragma unroll
    for (int off = 1; off < 64; off <<= 1) {
      const int v = __shfl_up(run, off, 64);
      if ((t & 63) >= off) run += v;
    }
    if ((t & 63) == 63) wcnt[t >> 6] = run;   // reuse wcnt as wave partials
  }
  __syncthreads();
  if (t < 256) {
    const int w = t >> 6;
    int addb = 0;
    if (w > 0) addb += wcnt[0];
    if (w > 1) addb += wcnt[1];
    if (w > 2) addb += wcnt[2];
    offs[t] = addb + run - ls;                // exclusive prefix
    if (t == 255) offs[256] = addb + run;
  }
  __syncthreads();
  if (t < 256) {
    const int base = t << 5;
    int rn = offs[t];
    for (int i = 0; i < 32; ++i) {
      rn += nb[base + i];
      if (nb[base + i]) starts[b * L_ + rn] = base + i;
    }
  }
  if (t == 0) { starts[b * L_ + 0] = 0; nlast[b] = offs[256]; }
}

// ---------------------------------------------------------------------------
// Segment softmax-merge (R5 v2) + bounds write (moved from k_select).
// ---------------------------------------------------------------------------
__global__ __launch_bounds__(256) void k_merge(const float* __restrict__ x,
    const float* __restrict__ mask, const float* __restrict__ e,
    const int* __restrict__ starts, const int* __restrict__ nlast,
    float* __restrict__ merged, float* __restrict__ bounds)
{
  const int idx = (blockIdx.x << 2) + (threadIdx.x >> 6);
  const int b   = idx >> 13;
  const int sid = idx & (L_ - 1);
  const int n = nlast[b];
  const int lane = threadIdx.x & 63;
  if (lane == 0)
    bounds[(size_t)b * L_ + sid] = (sid >= 1 && sid <= n) ? 1.0f : 0.0f;
  const int c0 = lane << 3;
  float* o = merged + (size_t)(b * L_ + sid) * D_ + c0;
  if (sid > n) {
    const float4 z = make_float4(0.f, 0.f, 0.f, 0.f);
    reinterpret_cast<float4*>(o)[0] = z;
    reinterpret_cast<float4*>(o)[1] = z;
    return;
  }
  const int t0 = starts[b * L_ + sid];
  const int t1 = (sid < n) ? starts[b * L_ + sid + 1] : L_;
  const int len = t1 - t0;
  const float* eb = e + b * L_;

  float acc[8] = {0,0,0,0,0,0,0,0};

  if (len <= 64) {
    // ---- whole segment in-wave: 1 coalesced e load + shfl reductions ----
    const float ev = (lane < len) ? eb[t0 + lane] : -INFINITY;
    float mx = ev;
#pragma unroll
    for (int off = 1; off < 64; off <<= 1)
      mx = fmaxf(mx, __shfl_xor(mx, off, 64));
    const float ex = expf(ev - mx);          // 0 for dead lanes
    float den = ex;
#pragma unroll
    for (int off = 1; off < 64; off <<= 1)
      den += __shfl_xor(den, off, 64);
    const float mk = (lane < len) ? mask[b * L_ + t0 + lane] : 0.f;
    const float scl = (ex / den) * mk;       // per-lane: weight of row t0+lane

    // ---- x-row loop with 2-deep load pipeline ----
    const float* xr = x + (size_t)(b * L_ + t0) * D_ + c0;
    float4 u0 = reinterpret_cast<const float4*>(xr)[0];
    float4 u1 = reinterpret_cast<const float4*>(xr)[1];
    for (int r = 0; r < len; ++r) {
      float4 n0, n1;
      if (r + 1 < len) {
        const float* xn = xr + (size_t)(r + 1) * D_;
        n0 = reinterpret_cast<const float4*>(xn)[0];
        n1 = reinterpret_cast<const float4*>(xn)[1];
      }
      const float sc = __shfl(scl, r, 64);
      acc[0] = fmaf(sc, u0.x, acc[0]); acc[1] = fmaf(sc, u0.y, acc[1]);
      acc[2] = fmaf(sc, u0.z, acc[2]); acc[3] = fmaf(sc, u0.w, acc[3]);
      acc[4] = fmaf(sc, u1.x, acc[4]); acc[5] = fmaf(sc, u1.y, acc[5]);
      acc[6] = fmaf(sc, u1.z, acc[6]); acc[7] = fmaf(sc, u1.w, acc[7]);
      u0 = n0; u1 = n1;
    }
  } else {
    // ---- fallback (len > 64): original serial path ----
    float mx = -INFINITY;
    for (int p = t0; p < t1; ++p) mx = fmaxf(mx, eb[p]);
    float den = 0.f;
    for (int p = t0; p < t1; ++p) den += expf(eb[p] - mx);
    for (int p = t0; p < t1; ++p) {
      const float wn = expf(eb[p] - mx) / den;
      const float sc = wn * mask[b * L_ + p];
      const float* xr = x + ((size_t)(b * L_ + p)) * D_ + c0;
      const float4 u0 = reinterpret_cast<const float4*>(xr)[0];
      const float4 u1 = reinterpret_cast<const float4*>(xr)[1];
      acc[0] = fmaf(sc, u0.x, acc[0]); acc[1] = fmaf(sc, u0.y, acc[1]);
      acc[2] = fmaf(sc, u0.z, acc[2]); acc[3] = fmaf(sc, u0.w, acc[3]);
      acc[4] = fmaf(sc, u1.x, acc[4]); acc[5] = fmaf(sc, u1.y, acc[5]);
      acc[6] = fmaf(sc, u1.z, acc[6]); acc[7] = fmaf(sc, u1.w, acc[7]);
    }
  }
  reinterpret_cast<float4*>(o)[0] = make_float4(acc[0], acc[1], acc[2], acc[3]);
  reinterpret_cast<float4*>(o)[1] = make_float4(acc[4], acc[5], acc[6], acc[7]);
}

// ---------------------------------------------------------------------------
extern "C" void kernel_launch(void* const* d_in, const int* in_sizes, int n_in,
                              void* d_out, int out_size, void* d_ws, size_t ws_size,
                              hipStream_t stream) {
  (void)in_sizes; (void)n_in; (void)out_size; (void)ws_size;
  const float* x    = (const float*)d_in[0];
  const float* mask = (const float*)d_in[1];
  const float* W1   = (const float*)d_in[2];
  const float* b1   = (const float*)d_in[3];
  const float* W2   = (const float*)d_in[4];
  const float* b2   = (const float*)d_in[5];
  const float* Wc   = (const float*)d_in[6];
  const float* bc   = (const float*)d_in[7];
  const float* Wb1  = (const float*)d_in[8];
  const float* bb1  = (const float*)d_in[9];
  const float* Wb2  = (const float*)d_in[10];
  const float* bb2  = (const float*)d_in[11];

  float* merged = (float*)d_out;
  float* bounds = (float*)d_out + (size_t)BL_ * D_;

  char* ws = (char*)d_ws;
  float* signal = (float*)(ws);
  float* e      = (float*)(ws + (size_t)BL_ * 4);
  int*   starts = (int*)  (ws + (size_t)BL_ * 8);
  int*   nlast  = (int*)  (ws + (size_t)BL_ * 12);

  k_signal<<<BL_ / TOK, 256, 0, stream>>>(x, mask, W1, b1, W2, b2, Wc, bc,
                                          Wb1, bb1, Wb2, bb2, signal, e);
  k_select<<<B_, 1024, 0, stream>>>(signal, starts, nlast);
  k_merge<<<BL_ / 4, 256, 0, stream>>>(x, mask, e, starts, nlast, merged, bounds);
}

// Round 8
// 299.798 us; speedup vs baseline: 1.0507x; 1.0057x over previous
//
#include <hip/hip_runtime.h>
#include <math.h>

#define B_  4
#define L_  8192
#define D_  512
#define BL_ (B_*L_)
#define TOK 64
#define XS  68            // 64 tok + 2 halo + 2 pad
#define KC  16
#define NCH (D_/KC)

// ---------------------------------------------------------------------------
// Signal + e — R1/R7 kernel (163-164 us, VGPR 84) + free-rider tail work:
//  - zeroes its 64 merged rows (1 float4 store/thread/chunk, issued after the
//    prefetch so the write-ack drains under the next chunk's compute)
//  - zeroes its 64 bounds entries (once)
//  - builds a per-row 256-bin top-byte histogram of signal (LDS, then ~4
//    nonzero global atomic flushes/block) so k_select can skip radix round 0.
// GEMM/conv/epilogue code and all numerics bit-identical to R7.
// ---------------------------------------------------------------------------
__global__ __launch_bounds__(256, 2) void k_signal(
    const float* __restrict__ x, const float* __restrict__ mask,
    const float* __restrict__ W1, const float* __restrict__ b1,
    const float* __restrict__ W2, const float* __restrict__ b2,
    const float* __restrict__ Wc, const float* __restrict__ bc,
    const float* __restrict__ Wb1, const float* __restrict__ bb1,
    const float* __restrict__ Wb2, const float* __restrict__ bb2,
    float* __restrict__ signal, float* __restrict__ e,
    unsigned int* __restrict__ hist,
    float* __restrict__ merged, float* __restrict__ bounds)
{
  __shared__ float ws1[KC][128];   // W1 chunk rows kc..kc+15
  __shared__ float wsb[KC][128];   // Wb1 x-part chunk
  __shared__ float wsp[8][128];    // Wb1 pf-part chunk (8 conv channels/chunk)
  __shared__ float xt[KC][XS];     // x transposed; col 64 = l0-1, 65 = l0+64
  __shared__ float pf[8][XS];      // conv out chunk

  const int t   = threadIdx.x;
  const int blk = blockIdx.x;          // 512 = 4 b x 128 tiles
  const int b   = blk >> 7;
  const int l0  = (blk & 127) << 6;
  const float* xb = x + (size_t)b * L_ * D_;

  const int jq = t & 31, tw = t >> 5;
  const int j0 = jq << 2, tok0 = tw << 3;

  // x-staging / e role: all 256 threads, one float4 per chunk
  const int stok = t >> 2, skk = t & 3;
  // conv role: out-ch oo_c, adjacent token pair (m2, m2+1)
  const int oo_c = t >> 5;             // 0..7
  const int m2   = (t & 31) << 1;      // 0,2,...,62
  const int cb_c = (oo_c >> 1) << 2;   // rel in-channel base {0,4,8,12}

  const int srow = t >> 5, sc4 = (t & 31) << 2;

  // ---- bounds zeroing for this block's 64 sids (once, fire-and-forget) ----
  if (t < 16) {
    float4* bz = reinterpret_cast<float4*>(bounds + (size_t)b * L_ + l0);
    bz[t] = make_float4(0.f, 0.f, 0.f, 0.f);
  }
  float4* mz = reinterpret_cast<float4*>(merged + (size_t)(b * L_ + l0) * D_);

  float a1[8][4], a2[8][4];
#pragma unroll
  for (int i = 0; i < 8; ++i)
#pragma unroll
    for (int j = 0; j < 4; ++j) { a1[i][j] = 0.f; a2[i][j] = 0.f; }
  float esacc = 0.f;

  // prefetch registers (next chunk)
  float4 r_w1a, r_w1b, r_wba, r_wbb, r_wp, r_xv, r_hv;
  float4 r_wc0, r_wc1, r_wc2;
  float  r_bc;

  auto LOAD = [&](int c) {
    const int kc = c << 4;
    r_w1a = *reinterpret_cast<const float4*>(W1  + (size_t)(kc + srow) * 128 + sc4);
    r_w1b = *reinterpret_cast<const float4*>(W1  + (size_t)(kc + 8 + srow) * 128 + sc4);
    r_wba = *reinterpret_cast<const float4*>(Wb1 + (size_t)(kc + srow) * 128 + sc4);
    r_wbb = *reinterpret_cast<const float4*>(Wb1 + (size_t)(kc + 8 + srow) * 128 + sc4);
    r_wp  = *reinterpret_cast<const float4*>(Wb1 + (size_t)(512 + (c << 3) + srow) * 128 + sc4);
    r_xv  = *reinterpret_cast<const float4*>(xb + (size_t)(l0 + stok) * D_ + kc + (skk << 2));
    if (t < 8) {
      const int hh = t >> 2, kk = t & 3;
      const int l = hh ? (l0 + TOK) : (l0 - 1);
      r_hv = make_float4(0.f, 0.f, 0.f, 0.f);
      if (l >= 0 && l < L_)
        r_hv = *reinterpret_cast<const float4*>(xb + (size_t)l * D_ + kc + (kk << 2));
    }
    const int o = (c << 3) + oo_c;
    const float* wcp = Wc + o * 12;
    r_wc0 = *reinterpret_cast<const float4*>(wcp);
    r_wc1 = *reinterpret_cast<const float4*>(wcp + 4);
    r_wc2 = *reinterpret_cast<const float4*>(wcp + 8);
    r_bc  = bc[o];
  };

  LOAD(0);

  for (int c = 0; c < NCH; ++c) {
    __syncthreads();                   // previous chunk fully consumed

    // ---- write staged registers into LDS ----
    *reinterpret_cast<float4*>(&ws1[srow][sc4])     = r_w1a;
    *reinterpret_cast<float4*>(&ws1[8 + srow][sc4]) = r_w1b;
    *reinterpret_cast<float4*>(&wsb[srow][sc4])     = r_wba;
    *reinterpret_cast<float4*>(&wsb[8 + srow][sc4]) = r_wbb;
    *reinterpret_cast<float4*>(&wsp[srow][sc4])     = r_wp;
    {
      const float4 v = r_xv;
      esacc = fmaf(v.x, v.x, esacc); esacc = fmaf(v.y, v.y, esacc);
      esacc = fmaf(v.z, v.z, esacc); esacc = fmaf(v.w, v.w, esacc);
      const int r = skk << 2;
      xt[r + 0][stok] = v.x; xt[r + 1][stok] = v.y;
      xt[r + 2][stok] = v.z; xt[r + 3][stok] = v.w;
    }
    if (t < 8) {
      const int hh = t >> 2, kk = t & 3;
      const int col = TOK + hh, r = kk << 2;
      xt[r + 0][col] = r_hv.x; xt[r + 1][col] = r_hv.y;
      xt[r + 2][col] = r_hv.z; xt[r + 3][col] = r_hv.w;
    }
    __syncthreads();                   // staged data visible

    // keep this chunk's conv weights before the prefetch overwrites them
    float wcl[12];
    wcl[0] = r_wc0.x; wcl[1]  = r_wc0.y; wcl[2]  = r_wc0.z; wcl[3]  = r_wc0.w;
    wcl[4] = r_wc1.x; wcl[5]  = r_wc1.y; wcl[6]  = r_wc1.z; wcl[7]  = r_wc1.w;
    wcl[8] = r_wc2.x; wcl[9]  = r_wc2.y; wcl[10] = r_wc2.z; wcl[11] = r_wc2.w;
    const float bcv = r_bc;

    if (c + 1 < NCH) LOAD(c + 1);      // issue next chunk's global loads

    // ---- merged-zero rider: 1 float4/thread/chunk, drains under compute ----
    mz[(c << 8) + t] = make_float4(0.f, 0.f, 0.f, 0.f);

    // ---- conv: out-ch (c*8+oo_c), tokens m2 and m2+1 ----
    {
      float pa = bcv, pb = bcv;
      const int tm1 = (m2 == 0) ? TOK : m2 - 1;
      const int tp2 = (m2 + 2 == TOK) ? TOK + 1 : m2 + 2;
#pragma unroll
      for (int i = 0; i < 4; ++i) {
        const float* row = &xt[cb_c + i][0];
        const float  xm1 = row[tm1];
        const float2 x01 = *reinterpret_cast<const float2*>(&row[m2]);
        const float  xp2 = row[tp2];
        pa = fmaf(xm1,   wcl[i * 3 + 0], pa);
        pa = fmaf(x01.x, wcl[i * 3 + 1], pa);
        pa = fmaf(x01.y, wcl[i * 3 + 2], pa);
        pb = fmaf(x01.x, wcl[i * 3 + 0], pb);
        pb = fmaf(x01.y, wcl[i * 3 + 1], pb);
        pb = fmaf(xp2,   wcl[i * 3 + 2], pb);
      }
      *reinterpret_cast<float2*>(&pf[oo_c][m2]) = make_float2(pa, pb);
    }

    // ---- GEMM x-part: 4 b128 -> 64 FMA per k ----
#pragma unroll 4
    for (int k = 0; k < KC; ++k) {
      const float4 w1 = *reinterpret_cast<const float4*>(&ws1[k][j0]);
      const float4 wb = *reinterpret_cast<const float4*>(&wsb[k][j0]);
      const float4 xa = *reinterpret_cast<const float4*>(&xt[k][tok0]);
      const float4 xc = *reinterpret_cast<const float4*>(&xt[k][tok0 + 4]);
      const float xs8[8] = {xa.x, xa.y, xa.z, xa.w, xc.x, xc.y, xc.z, xc.w};
#pragma unroll
      for (int i = 0; i < 8; ++i) {
        a1[i][0] = fmaf(xs8[i], w1.x, a1[i][0]);
        a1[i][1] = fmaf(xs8[i], w1.y, a1[i][1]);
        a1[i][2] = fmaf(xs8[i], w1.z, a1[i][2]);
        a1[i][3] = fmaf(xs8[i], w1.w, a1[i][3]);
        a2[i][0] = fmaf(xs8[i], wb.x, a2[i][0]);
        a2[i][1] = fmaf(xs8[i], wb.y, a2[i][1]);
        a2[i][2] = fmaf(xs8[i], wb.z, a2[i][2]);
        a2[i][3] = fmaf(xs8[i], wb.w, a2[i][3]);
      }
    }
    __syncthreads();                   // pf writes visible

    // ---- GEMM pf-part ----
#pragma unroll 2
    for (int oo = 0; oo < 8; ++oo) {
      const float4 wp = *reinterpret_cast<const float4*>(&wsp[oo][j0]);
      const float4 pa4 = *reinterpret_cast<const float4*>(&pf[oo][tok0]);
      const float4 pb4 = *reinterpret_cast<const float4*>(&pf[oo][tok0 + 4]);
      const float ps8[8] = {pa4.x, pa4.y, pa4.z, pa4.w, pb4.x, pb4.y, pb4.z, pb4.w};
#pragma unroll
      for (int i = 0; i < 8; ++i) {
        a2[i][0] = fmaf(ps8[i], wp.x, a2[i][0]);
        a2[i][1] = fmaf(ps8[i], wp.y, a2[i][1]);
        a2[i][2] = fmaf(ps8[i], wp.z, a2[i][2]);
        a2[i][3] = fmaf(ps8[i], wp.w, a2[i][3]);
      }
    }
  }

  // ---- epilogue: relu, project, cross-jq reduce, sigmoid ----
  float sigv[8];                       // jq==0 lanes: signal of tokens i=0..7
#pragma unroll
  for (int i = 0; i < 8; ++i) sigv[i] = 0.f;
  {
    float b1v[4], w2v[4], bbv[4], wv2[4];
#pragma unroll
    for (int jj = 0; jj < 4; ++jj) {
      b1v[jj] = b1[j0 + jj];  w2v[jj] = W2[j0 + jj];
      bbv[jj] = bb1[j0 + jj]; wv2[jj] = Wb2[j0 + jj];
    }
    const float bias2 = b2[0], biasb2 = bb2[0];
#pragma unroll
    for (int i = 0; i < 8; ++i) {
      float p1 = 0.f, p2 = 0.f;
#pragma unroll
      for (int jj = 0; jj < 4; ++jj) {
        const float h1 = a1[i][jj] + b1v[jj];
        if (h1 > 0.f) p1 = fmaf(h1, w2v[jj], p1);
        const float h2 = a2[i][jj] + bbv[jj];
        if (h2 > 0.f) p2 = fmaf(h2, wv2[jj], p2);
      }
#pragma unroll
      for (int off = 1; off < 32; off <<= 1) {
        p1 += __shfl_xor(p1, off, 64);
        p2 += __shfl_xor(p2, off, 64);
      }
      if (jq == 0) {
        const int gi = b * L_ + l0 + tok0 + i;
        const float content = 1.f / (1.f + expf(-(p1 + bias2)));
        const float bscore  = 1.f / (1.f + expf(-(p2 + biasb2)));
        const float s = content * (1.f - bscore) * mask[gi];
        sigv[i] = s;
        signal[gi] = s;
      }
    }
  }

  // ---- e epilogue: reduce over the 4 skk lanes of each token ----
  {
    float es = esacc;
    es += __shfl_xor(es, 1, 64);
    es += __shfl_xor(es, 2, 64);
    if (skk == 0) {
      const int gi = b * L_ + l0 + stok;
      const float m = mask[gi];
      e[gi] = m * m * es;
    }
  }

  // ---- per-block signal top-byte histogram -> global (radix round 0) ----
  {
    __syncthreads();
    unsigned int* hl = reinterpret_cast<unsigned int*>(&xt[0][0]);
    hl[t & 255] = 0u;                  // 256 threads -> all bins zeroed
    __syncthreads();
    if (jq == 0) {
#pragma unroll
      for (int i = 0; i < 8; ++i) {
        const unsigned int u = __float_as_uint(sigv[i]);
        const unsigned int key = (u & 0x80000000u) ? ~u : (u | 0x80000000u);
        atomicAdd(&hl[key >> 24], 1u);
      }
    }
    __syncthreads();
    const unsigned int cnt = hl[t & 255];
    if (cnt) atomicAdd(&hist[(b << 8) + (t & 255)], cnt);
  }
}

// ---------------------------------------------------------------------------
// Fused quantile + enforce. One block (1024 thr) per batch row.
// Radix round 0 replaced by the k_signal-built histogram (bit-identical
// counts); rounds 1-3 unchanged. Prefix scan wave-parallel.
// ---------------------------------------------------------------------------
__device__ __forceinline__ int chain_sim(unsigned long long w, int from) {
  int last = -1;
  while (from < 64) {
    const unsigned long long m = w & (~0ull << from);
    if (m == 0ull) break;
    const int p = __ffsll(m) - 1;
    last = p;
    from = p + 4;
  }
  return last;
}

__global__ __launch_bounds__(1024) void k_select(
    const float* __restrict__ signal, const unsigned int* __restrict__ hist,
    int* __restrict__ starts, int* __restrict__ nlast)
{
  __shared__ unsigned int bins[4][256];
  __shared__ unsigned int sel_prefix;
  __shared__ int sel_rank;
  __shared__ float sh_thr;
  __shared__ unsigned int wmin[16];
  __shared__ int wcnt[16];
  __shared__ unsigned long long cw[128];
  __shared__ unsigned char nb[L_];
  __shared__ signed char tbl[128][4];
  __shared__ int st_in[128];
  __shared__ int offs[257];

  const int b = blockIdx.x, t = threadIdx.x;
  const int wv = t >> 6, lane = t & 63;
  const float* s = signal + b * L_;

  float val[8];
  unsigned int key[8];
#pragma unroll
  for (int i = 0; i < 8; ++i) {
    val[i] = s[(i << 10) + t];
    const unsigned int u = __float_as_uint(val[i]);
    key[i] = (u & 0x80000000u) ? ~u : (u | 0x80000000u);
  }

  // ---- round 0 from precomputed histogram ----
  if (t < 256) bins[0][t] = hist[(b << 8) + t];
  __syncthreads();
  if (t < 64) {
    const unsigned int c0 = bins[0][(t << 2) + 0], c1 = bins[0][(t << 2) + 1];
    const unsigned int c2 = bins[0][(t << 2) + 2], c3 = bins[0][(t << 2) + 3];
    const unsigned int lsum = c0 + c1 + c2 + c3;
    unsigned int run = lsum;
#pragma unroll
    for (int off = 1; off < 64; off <<= 1) {
      const unsigned int v = __shfl_up(run, off, 64);
      if (t >= off) run += v;
    }
    const int r = 5733;                // rank = floor(0.7*(L-1))
    if (r >= (int)(run - lsum) && r < (int)run) {
      int rr = r - (int)(run - lsum);
      unsigned int cbin;
      if (rr < (int)c0) { cbin = 0; }
      else if (rr < (int)(c0 + c1)) { cbin = 1; rr -= (int)c0; }
      else if (rr < (int)(c0 + c1 + c2)) { cbin = 2; rr -= (int)(c0 + c1); }
      else { cbin = 3; rr -= (int)(c0 + c1 + c2); }
      sel_rank = rr;
      sel_prefix = (unsigned int)(t << 2) | cbin;
    }
  }
  __syncthreads();

  // ---- radix rounds 1..3 ----
  for (int round = 1; round < 4; ++round) {
    reinterpret_cast<unsigned int*>(bins)[t] = 0u;
    __syncthreads();
    const unsigned int pre = sel_prefix;
    const int shift = 24 - 8 * round;
#pragma unroll
    for (int i = 0; i < 8; ++i) {
      if ((key[i] >> (shift + 8)) == pre)
        atomicAdd(&bins[t >> 8][(key[i] >> shift) & 255u], 1u);
    }
    __syncthreads();
    if (t < 256)
      bins[0][t] = bins[0][t] + bins[1][t] + bins[2][t] + bins[3][t];
    __syncthreads();
    if (t < 64) {
      const unsigned int c0 = bins[0][(t << 2) + 0], c1 = bins[0][(t << 2) + 1];
      const unsigned int c2 = bins[0][(t << 2) + 2], c3 = bins[0][(t << 2) + 3];
      const unsigned int lsum = c0 + c1 + c2 + c3;
      unsigned int run = lsum;
#pragma unroll
      for (int off = 1; off < 64; off <<= 1) {
        const unsigned int v = __shfl_up(run, off, 64);
        if (t >= off) run += v;
      }
      const int r = sel_rank;
      if (r >= (int)(run - lsum) && r < (int)run) {
        int rr = r - (int)(run - lsum);
        unsigned int cbin;
        if (rr < (int)c0) { cbin = 0; }
        else if (rr < (int)(c0 + c1)) { cbin = 1; rr -= (int)c0; }
        else if (rr < (int)(c0 + c1 + c2)) { cbin = 2; rr -= (int)(c0 + c1); }
        else { cbin = 3; rr -= (int)(c0 + c1 + c2); }
        sel_rank = rr;
        sel_prefix = (pre << 8) | ((unsigned int)(t << 2) | cbin);
      }
    }
    __syncthreads();
  }
  const unsigned int k0 = sel_prefix;

  // ---- successor: count <=k0 and min of keys > k0 (tie-safe) ----
  {
    int cle = 0;
    unsigned int mgt = 0xFFFFFFFFu;
#pragma unroll
    for (int i = 0; i < 8; ++i) {
      if (key[i] <= k0) ++cle;
      else mgt = min(mgt, key[i]);
    }
#pragma unroll
    for (int off = 1; off < 64; off <<= 1) {
      cle += __shfl_xor(cle, off, 64);
      mgt = min(mgt, (unsigned int)__shfl_xor((int)mgt, off, 64));
    }
    if (lane == 0) { wcnt[wv] = cle; wmin[wv] = mgt; }
    __syncthreads();
    if (t == 0) {
      int C = 0; unsigned int M = 0xFFFFFFFFu;
      for (int g = 0; g < 16; ++g) { C += wcnt[g]; M = min(M, wmin[g]); }
      const unsigned int k1 = (C >= 5735) ? k0 : M;
      const unsigned int u0 = (k0 & 0x80000000u) ? (k0 & 0x7fffffffu) : ~k0;
      const unsigned int u1 = (k1 & 0x80000000u) ? (k1 & 0x7fffffffu) : ~k1;
      const float v0 = __uint_as_float(u0);
      const float v1 = __uint_as_float(u1);
      const float g = 0.7f * 8191.0f - 5733.0f;
      sh_thr = v0 + g * (v1 - v0);
    }
    __syncthreads();
  }
  const float thr = sh_thr;

  // ---- candidate bitmap from register values ----
#pragma unroll
  for (int i = 0; i < 8; ++i) {
    const unsigned long long m = __ballot(val[i] < thr);
    if (lane == 0) cw[(i << 4) + wv] = m;
  }
  {
    const int base = t << 3;
#pragma unroll
    for (int i = 0; i < 8; ++i) nb[base + i] = 0;
  }
  __syncthreads();
  if (t == 0) cw[127] |= (1ull << 63);   // forced candidate at L-1
  __syncthreads();

  // ---- (1) per-64-block transition tables ----
  if (t < 512) {
    const int blk = t >> 2, cls = t & 3;
    tbl[blk][cls] = (signed char)chain_sim(cw[blk], cls);
  }
  __syncthreads();

  // ---- (2) serial 128-step state scan ----
  if (t == 0) {
    int st = 0;
    for (int blk = 0; blk < 128; ++blk) {
      const int bs = blk << 6;
      st_in[blk] = st;
      int pl;
      if (blk == 0) {
        pl = chain_sim(cw[0], 4);
      } else {
        int off = st + 4 - bs;
        if (off < 0) off = 0;
        pl = tbl[blk][off];
      }
      if (pl >= 0) st = bs + pl;
    }
  }
  __syncthreads();

  // ---- (3) parallel emission of acceptance + split bytes ----
  if (t < 128) {
    const int bs = t << 6;
    const unsigned long long w = cw[t];
    int st = st_in[t];
    int from = st + 4 - bs;
    if (from < 0) from = 0;
    while (from < 64) {
      const unsigned long long m = w & (~0ull << from);
      if (m == 0ull) break;
      const int p_rel = __ffsll(m) - 1;
      const int p = bs + p_rel;
      nb[p] = 1;
      const int ps = p - st;
      const int k = (ps + 15) >> 4;
      if (k > 1) {
        int sz = ps / k; if (sz < 1) sz = 1;
        for (int j = 1; j < k; ++j) nb[st + j * sz] = 1;
      }
      st = p;
      from = p_rel + 4;
    }
  }
  __syncthreads();

  // ---- wave-parallel prefix scan over 256 x 32-token sums ----
  int ls = 0, run = 0;
  if (t < 256) {
    const int base = t << 5;
    for (int i = 0; i < 32; ++i) ls += nb[base + i];
    run = ls;
#pragma unroll
    for (int off = 1; off < 64; off <<= 1) {
      const int v = __shfl_up(run, off, 64);
      if ((t & 63) >= off) run += v;
    }
    if ((t & 63) == 63) wcnt[t >> 6] = run;   // reuse wcnt as wave partials
  }
  __syncthreads();
  if (t < 256) {
    const int w = t >> 6;
    int addb = 0;
    if (w > 0) addb += wcnt[0];
    if (w > 1) addb += wcnt[1];
    if (w > 2) addb += wcnt[2];
    offs[t] = addb + run - ls;                // exclusive prefix
    if (t == 255) offs[256] = addb + run;
  }
  __syncthreads();
  if (t < 256) {
    const int base = t << 5;
    int rn = offs[t];
    for (int i = 0; i < 32; ++i) {
      rn += nb[base + i];
      if (nb[base + i]) starts[b * L_ + rn] = base + i;
    }
  }
  if (t == 0) { starts[b * L_ + 0] = 0; nlast[b] = offs[256]; }
}

// ---------------------------------------------------------------------------
// Segment softmax-merge: live sids only (merged/bounds pre-zeroed by
// k_signal). Dead sids exit after one nlast read.
// ---------------------------------------------------------------------------
__global__ __launch_bounds__(256) void k_merge(const float* __restrict__ x,
    const float* __restrict__ mask, const float* __restrict__ e,
    const int* __restrict__ starts, const int* __restrict__ nlast,
    float* __restrict__ merged, float* __restrict__ bounds)
{
  const int idx = (blockIdx.x << 2) + (threadIdx.x >> 6);
  const int b   = idx >> 13;
  const int sid = idx & (L_ - 1);
  const int n = nlast[b];
  if (sid > n) return;                 // merged row and bounds already zero
  const int lane = threadIdx.x & 63;
  if (lane == 0 && sid >= 1)
    bounds[(size_t)b * L_ + sid] = 1.0f;
  const int c0 = lane << 3;
  float* o = merged + (size_t)(b * L_ + sid) * D_ + c0;
  const int t0 = starts[b * L_ + sid];
  const int t1 = (sid < n) ? starts[b * L_ + sid + 1] : L_;
  const int len = t1 - t0;
  const float* eb = e + b * L_;

  float acc[8] = {0,0,0,0,0,0,0,0};

  if (len <= 64) {
    // ---- whole segment in-wave: 1 coalesced e load + shfl reductions ----
    const float ev = (lane < len) ? eb[t0 + lane] : -INFINITY;
    float mx = ev;
#pragma unroll
    for (int off = 1; off < 64; off <<= 1)
      mx = fmaxf(mx, __shfl_xor(mx, off, 64));
    const float ex = expf(ev - mx);          // 0 for dead lanes
    float den = ex;
#pragma unroll
    for (int off = 1; off < 64; off <<= 1)
      den += __shfl_xor(den, off, 64);
    const float mk = (lane < len) ? mask[b * L_ + t0 + lane] : 0.f;
    const float scl = (ex / den) * mk;       // per-lane: weight of row t0+lane

    // ---- x-row loop with 2-deep load pipeline ----
    const float* xr = x + (size_t)(b * L_ + t0) * D_ + c0;
    float4 u0 = reinterpret_cast<const float4*>(xr)[0];
    float4 u1 = reinterpret_cast<const float4*>(xr)[1];
    for (int r = 0; r < len; ++r) {
      float4 n0, n1;
      if (r + 1 < len) {
        const float* xn = xr + (size_t)(r + 1) * D_;
        n0 = reinterpret_cast<const float4*>(xn)[0];
        n1 = reinterpret_cast<const float4*>(xn)[1];
      }
      const float sc = __shfl(scl, r, 64);
      acc[0] = fmaf(sc, u0.x, acc[0]); acc[1] = fmaf(sc, u0.y, acc[1]);
      acc[2] = fmaf(sc, u0.z, acc[2]); acc[3] = fmaf(sc, u0.w, acc[3]);
      acc[4] = fmaf(sc, u1.x, acc[4]); acc[5] = fmaf(sc, u1.y, acc[5]);
      acc[6] = fmaf(sc, u1.z, acc[6]); acc[7] = fmaf(sc, u1.w, acc[7]);
      u0 = n0; u1 = n1;
    }
  } else {
    // ---- fallback (len > 64): original serial path ----
    float mx = -INFINITY;
    for (int p = t0; p < t1; ++p) mx = fmaxf(mx, eb[p]);
    float den = 0.f;
    for (int p = t0; p < t1; ++p) den += expf(eb[p] - mx);
    for (int p = t0; p < t1; ++p) {
      const float wn = expf(eb[p] - mx) / den;
      const float sc = wn * mask[b * L_ + p];
      const float* xr = x + ((size_t)(b * L_ + p)) * D_ + c0;
      const float4 u0 = reinterpret_cast<const float4*>(xr)[0];
      const float4 u1 = reinterpret_cast<const float4*>(xr)[1];
      acc[0] = fmaf(sc, u0.x, acc[0]); acc[1] = fmaf(sc, u0.y, acc[1]);
      acc[2] = fmaf(sc, u0.z, acc[2]); acc[3] = fmaf(sc, u0.w, acc[3]);
      acc[4] = fmaf(sc, u1.x, acc[4]); acc[5] = fmaf(sc, u1.y, acc[5]);
      acc[6] = fmaf(sc, u1.z, acc[6]); acc[7] = fmaf(sc, u1.w, acc[7]);
    }
  }
  reinterpret_cast<float4*>(o)[0] = make_float4(acc[0], acc[1], acc[2], acc[3]);
  reinterpret_cast<float4*>(o)[1] = make_float4(acc[4], acc[5], acc[6], acc[7]);
}

// ---------------------------------------------------------------------------
extern "C" void kernel_launch(void* const* d_in, const int* in_sizes, int n_in,
                              void* d_out, int out_size, void* d_ws, size_t ws_size,
                              hipStream_t stream) {
  (void)in_sizes; (void)n_in; (void)out_size; (void)ws_size;
  const float* x    = (const float*)d_in[0];
  const float* mask = (const float*)d_in[1];
  const float* W1   = (const float*)d_in[2];
  const float* b1   = (const float*)d_in[3];
  const float* W2   = (const float*)d_in[4];
  const float* b2   = (const float*)d_in[5];
  const float* Wc   = (const float*)d_in[6];
  const float* bc   = (const float*)d_in[7];
  const float* Wb1  = (const float*)d_in[8];
  const float* bb1  = (const float*)d_in[9];
  const float* Wb2  = (const float*)d_in[10];
  const float* bb2  = (const float*)d_in[11];

  float* merged = (float*)d_out;
  float* bounds = (float*)d_out + (size_t)BL_ * D_;

  char* ws = (char*)d_ws;
  float*        signal = (float*)(ws);
  float*        e      = (float*)(ws + (size_t)BL_ * 4);
  int*          starts = (int*)  (ws + (size_t)BL_ * 8);
  int*          nlast  = (int*)  (ws + (size_t)BL_ * 12);
  unsigned int* hist   = (unsigned int*)(ws + (size_t)BL_ * 12 + 256);

  hipMemsetAsync(hist, 0, B_ * 256 * sizeof(unsigned int), stream);
  k_signal<<<BL_ / TOK, 256, 0, stream>>>(x, mask, W1, b1, W2, b2, Wc, bc,
                                          Wb1, bb1, Wb2, bb2, signal, e,
                                          hist, merged, bounds);
  k_select<<<B_, 1024, 0, stream>>>(signal, hist, starts, nlast);
  k_merge<<<BL_ / 4, 256, 0, stream>>>(x, mask, e, starts, nlast, merged, bounds);
}

// Round 9
// 292.117 us; speedup vs baseline: 1.0783x; 1.0263x over previous
//
#include <hip/hip_runtime.h>
#include <math.h>

#define B_  4
#define L_  8192
#define D_  512
#define BL_ (B_*L_)
#define TOK 64
#define XS  68            // 64 tok + 2 halo + 2 pad
#define KC  16
#define NCH (D_/KC)

// ---------------------------------------------------------------------------
// Signal + e — R1 core (163-164 us) + riders:
//  - zeroes merged rows (1 float4/thread/chunk, drains under compute)
//  - zeroes bounds entries (once)
//  - 16-bit-key histogram of signal via direct global atomics (transposed
//    bin layout, 8 atomics per jq==0 lane in the epilogue) so k_select can
//    skip radix rounds 0 AND 1 (both are serialized-atomic hotspots because
//    signal values concentrate near 0.25 and share their top 2 key bytes).
// GEMM/conv/epilogue numerics bit-identical to R7/R8.
// ---------------------------------------------------------------------------
__global__ __launch_bounds__(256, 2) void k_signal(
    const float* __restrict__ x, const float* __restrict__ mask,
    const float* __restrict__ W1, const float* __restrict__ b1,
    const float* __restrict__ W2, const float* __restrict__ b2,
    const float* __restrict__ Wc, const float* __restrict__ bc,
    const float* __restrict__ Wb1, const float* __restrict__ bb1,
    const float* __restrict__ Wb2, const float* __restrict__ bb2,
    float* __restrict__ signal, float* __restrict__ e,
    unsigned int* __restrict__ hist16,
    float* __restrict__ merged, float* __restrict__ bounds)
{
  __shared__ float ws1[KC][128];   // W1 chunk rows kc..kc+15
  __shared__ float wsb[KC][128];   // Wb1 x-part chunk
  __shared__ float wsp[8][128];    // Wb1 pf-part chunk (8 conv channels/chunk)
  __shared__ float xt[KC][XS];     // x transposed; col 64 = l0-1, 65 = l0+64
  __shared__ float pf[8][XS];      // conv out chunk

  const int t   = threadIdx.x;
  const int blk = blockIdx.x;          // 512 = 4 b x 128 tiles
  const int b   = blk >> 7;
  const int l0  = (blk & 127) << 6;
  const float* xb = x + (size_t)b * L_ * D_;

  const int jq = t & 31, tw = t >> 5;
  const int j0 = jq << 2, tok0 = tw << 3;

  // x-staging / e role: all 256 threads, one float4 per chunk
  const int stok = t >> 2, skk = t & 3;
  // conv role: out-ch oo_c, adjacent token pair (m2, m2+1)
  const int oo_c = t >> 5;             // 0..7
  const int m2   = (t & 31) << 1;      // 0,2,...,62
  const int cb_c = (oo_c >> 1) << 2;   // rel in-channel base {0,4,8,12}

  const int srow = t >> 5, sc4 = (t & 31) << 2;

  // ---- bounds zeroing for this block's 64 sids (once, fire-and-forget) ----
  if (t < 16) {
    float4* bz = reinterpret_cast<float4*>(bounds + (size_t)b * L_ + l0);
    bz[t] = make_float4(0.f, 0.f, 0.f, 0.f);
  }
  float4* mz = reinterpret_cast<float4*>(merged + (size_t)(b * L_ + l0) * D_);

  float a1[8][4], a2[8][4];
#pragma unroll
  for (int i = 0; i < 8; ++i)
#pragma unroll
    for (int j = 0; j < 4; ++j) { a1[i][j] = 0.f; a2[i][j] = 0.f; }
  float esacc = 0.f;

  // prefetch registers (next chunk)
  float4 r_w1a, r_w1b, r_wba, r_wbb, r_wp, r_xv, r_hv;
  float4 r_wc0, r_wc1, r_wc2;
  float  r_bc;

  auto LOAD = [&](int c) {
    const int kc = c << 4;
    r_w1a = *reinterpret_cast<const float4*>(W1  + (size_t)(kc + srow) * 128 + sc4);
    r_w1b = *reinterpret_cast<const float4*>(W1  + (size_t)(kc + 8 + srow) * 128 + sc4);
    r_wba = *reinterpret_cast<const float4*>(Wb1 + (size_t)(kc + srow) * 128 + sc4);
    r_wbb = *reinterpret_cast<const float4*>(Wb1 + (size_t)(kc + 8 + srow) * 128 + sc4);
    r_wp  = *reinterpret_cast<const float4*>(Wb1 + (size_t)(512 + (c << 3) + srow) * 128 + sc4);
    r_xv  = *reinterpret_cast<const float4*>(xb + (size_t)(l0 + stok) * D_ + kc + (skk << 2));
    if (t < 8) {
      const int hh = t >> 2, kk = t & 3;
      const int l = hh ? (l0 + TOK) : (l0 - 1);
      r_hv = make_float4(0.f, 0.f, 0.f, 0.f);
      if (l >= 0 && l < L_)
        r_hv = *reinterpret_cast<const float4*>(xb + (size_t)l * D_ + kc + (kk << 2));
    }
    const int o = (c << 3) + oo_c;
    const float* wcp = Wc + o * 12;
    r_wc0 = *reinterpret_cast<const float4*>(wcp);
    r_wc1 = *reinterpret_cast<const float4*>(wcp + 4);
    r_wc2 = *reinterpret_cast<const float4*>(wcp + 8);
    r_bc  = bc[o];
  };

  LOAD(0);

  for (int c = 0; c < NCH; ++c) {
    __syncthreads();                   // previous chunk fully consumed

    // ---- write staged registers into LDS ----
    *reinterpret_cast<float4*>(&ws1[srow][sc4])     = r_w1a;
    *reinterpret_cast<float4*>(&ws1[8 + srow][sc4]) = r_w1b;
    *reinterpret_cast<float4*>(&wsb[srow][sc4])     = r_wba;
    *reinterpret_cast<float4*>(&wsb[8 + srow][sc4]) = r_wbb;
    *reinterpret_cast<float4*>(&wsp[srow][sc4])     = r_wp;
    {
      const float4 v = r_xv;
      esacc = fmaf(v.x, v.x, esacc); esacc = fmaf(v.y, v.y, esacc);
      esacc = fmaf(v.z, v.z, esacc); esacc = fmaf(v.w, v.w, esacc);
      const int r = skk << 2;
      xt[r + 0][stok] = v.x; xt[r + 1][stok] = v.y;
      xt[r + 2][stok] = v.z; xt[r + 3][stok] = v.w;
    }
    if (t < 8) {
      const int hh = t >> 2, kk = t & 3;
      const int col = TOK + hh, r = kk << 2;
      xt[r + 0][col] = r_hv.x; xt[r + 1][col] = r_hv.y;
      xt[r + 2][col] = r_hv.z; xt[r + 3][col] = r_hv.w;
    }
    __syncthreads();                   // staged data visible

    // keep this chunk's conv weights before the prefetch overwrites them
    float wcl[12];
    wcl[0] = r_wc0.x; wcl[1]  = r_wc0.y; wcl[2]  = r_wc0.z; wcl[3]  = r_wc0.w;
    wcl[4] = r_wc1.x; wcl[5]  = r_wc1.y; wcl[6]  = r_wc1.z; wcl[7]  = r_wc1.w;
    wcl[8] = r_wc2.x; wcl[9]  = r_wc2.y; wcl[10] = r_wc2.z; wcl[11] = r_wc2.w;
    const float bcv = r_bc;

    if (c + 1 < NCH) LOAD(c + 1);      // issue next chunk's global loads

    // ---- merged-zero rider: 1 float4/thread/chunk, drains under compute ----
    mz[(c << 8) + t] = make_float4(0.f, 0.f, 0.f, 0.f);

    // ---- conv: out-ch (c*8+oo_c), tokens m2 and m2+1 ----
    {
      float pa = bcv, pb = bcv;
      const int tm1 = (m2 == 0) ? TOK : m2 - 1;
      const int tp2 = (m2 + 2 == TOK) ? TOK + 1 : m2 + 2;
#pragma unroll
      for (int i = 0; i < 4; ++i) {
        const float* row = &xt[cb_c + i][0];
        const float  xm1 = row[tm1];
        const float2 x01 = *reinterpret_cast<const float2*>(&row[m2]);
        const float  xp2 = row[tp2];
        pa = fmaf(xm1,   wcl[i * 3 + 0], pa);
        pa = fmaf(x01.x, wcl[i * 3 + 1], pa);
        pa = fmaf(x01.y, wcl[i * 3 + 2], pa);
        pb = fmaf(x01.x, wcl[i * 3 + 0], pb);
        pb = fmaf(x01.y, wcl[i * 3 + 1], pb);
        pb = fmaf(xp2,   wcl[i * 3 + 2], pb);
      }
      *reinterpret_cast<float2*>(&pf[oo_c][m2]) = make_float2(pa, pb);
    }

    // ---- GEMM x-part: 4 b128 -> 64 FMA per k ----
#pragma unroll 4
    for (int k = 0; k < KC; ++k) {
      const float4 w1 = *reinterpret_cast<const float4*>(&ws1[k][j0]);
      const float4 wb = *reinterpret_cast<const float4*>(&wsb[k][j0]);
      const float4 xa = *reinterpret_cast<const float4*>(&xt[k][tok0]);
      const float4 xc = *reinterpret_cast<const float4*>(&xt[k][tok0 + 4]);
      const float xs8[8] = {xa.x, xa.y, xa.z, xa.w, xc.x, xc.y, xc.z, xc.w};
#pragma unroll
      for (int i = 0; i < 8; ++i) {
        a1[i][0] = fmaf(xs8[i], w1.x, a1[i][0]);
        a1[i][1] = fmaf(xs8[i], w1.y, a1[i][1]);
        a1[i][2] = fmaf(xs8[i], w1.z, a1[i][2]);
        a1[i][3] = fmaf(xs8[i], w1.w, a1[i][3]);
        a2[i][0] = fmaf(xs8[i], wb.x, a2[i][0]);
        a2[i][1] = fmaf(xs8[i], wb.y, a2[i][1]);
        a2[i][2] = fmaf(xs8[i], wb.z, a2[i][2]);
        a2[i][3] = fmaf(xs8[i], wb.w, a2[i][3]);
      }
    }
    __syncthreads();                   // pf writes visible

    // ---- GEMM pf-part ----
#pragma unroll 2
    for (int oo = 0; oo < 8; ++oo) {
      const float4 wp = *reinterpret_cast<const float4*>(&wsp[oo][j0]);
      const float4 pa4 = *reinterpret_cast<const float4*>(&pf[oo][tok0]);
      const float4 pb4 = *reinterpret_cast<const float4*>(&pf[oo][tok0 + 4]);
      const float ps8[8] = {pa4.x, pa4.y, pa4.z, pa4.w, pb4.x, pb4.y, pb4.z, pb4.w};
#pragma unroll
      for (int i = 0; i < 8; ++i) {
        a2[i][0] = fmaf(ps8[i], wp.x, a2[i][0]);
        a2[i][1] = fmaf(ps8[i], wp.y, a2[i][1]);
        a2[i][2] = fmaf(ps8[i], wp.z, a2[i][2]);
        a2[i][3] = fmaf(ps8[i], wp.w, a2[i][3]);
      }
    }
  }

  // ---- epilogue: relu, project, cross-jq reduce, sigmoid, hist16 ----
  {
    float b1v[4], w2v[4], bbv[4], wv2[4];
#pragma unroll
    for (int jj = 0; jj < 4; ++jj) {
      b1v[jj] = b1[j0 + jj];  w2v[jj] = W2[j0 + jj];
      bbv[jj] = bb1[j0 + jj]; wv2[jj] = Wb2[j0 + jj];
    }
    const float bias2 = b2[0], biasb2 = bb2[0];
#pragma unroll
    for (int i = 0; i < 8; ++i) {
      float p1 = 0.f, p2 = 0.f;
#pragma unroll
      for (int jj = 0; jj < 4; ++jj) {
        const float h1 = a1[i][jj] + b1v[jj];
        if (h1 > 0.f) p1 = fmaf(h1, w2v[jj], p1);
        const float h2 = a2[i][jj] + bbv[jj];
        if (h2 > 0.f) p2 = fmaf(h2, wv2[jj], p2);
      }
#pragma unroll
      for (int off = 1; off < 32; off <<= 1) {
        p1 += __shfl_xor(p1, off, 64);
        p2 += __shfl_xor(p2, off, 64);
      }
      if (jq == 0) {
        const int gi = b * L_ + l0 + tok0 + i;
        const float content = 1.f / (1.f + expf(-(p1 + bias2)));
        const float bscore  = 1.f / (1.f + expf(-(p2 + biasb2)));
        const float s = content * (1.f - bscore) * mask[gi];
        signal[gi] = s;
        const unsigned int u = __float_as_uint(s);
        const unsigned int key = (u & 0x80000000u) ? ~u : (u | 0x80000000u);
        const unsigned int bb16 = key >> 16;
        // transposed bin layout: loc = (bb&63)*1024 + (bb>>6)  (coalesced scan)
        atomicAdd(&hist16[((unsigned)b << 16) | ((bb16 & 63u) << 10) | (bb16 >> 6)], 1u);
      }
    }
  }

  // ---- e epilogue: reduce over the 4 skk lanes of each token ----
  {
    float es = esacc;
    es += __shfl_xor(es, 1, 64);
    es += __shfl_xor(es, 2, 64);
    if (skk == 0) {
      const int gi = b * L_ + l0 + stok;
      const float m = mask[gi];
      e[gi] = m * m * es;
    }
  }
}

// ---------------------------------------------------------------------------
// Fused quantile + enforce. One block (1024 thr) per batch row.
// Rounds 0-1 replaced by a two-level scan of the 16-bit histogram built in
// k_signal (bit-identical counts); rounds 2-3 unchanged.
// ---------------------------------------------------------------------------
__device__ __forceinline__ int chain_sim(unsigned long long w, int from) {
  int last = -1;
  while (from < 64) {
    const unsigned long long m = w & (~0ull << from);
    if (m == 0ull) break;
    const int p = __ffsll(m) - 1;
    last = p;
    from = p + 4;
  }
  return last;
}

__global__ __launch_bounds__(1024) void k_select(
    const float* __restrict__ signal, const unsigned int* __restrict__ hist16,
    int* __restrict__ starts, int* __restrict__ nlast)
{
  __shared__ unsigned int bins[4][256];
  __shared__ unsigned int sel_prefix;
  __shared__ int sel_rank;
  __shared__ int sel_tt, sel_rr;
  __shared__ unsigned int wpart[16];
  __shared__ float sh_thr;
  __shared__ unsigned int wmin[16];
  __shared__ int wcnt[16];
  __shared__ unsigned long long cw[128];
  __shared__ unsigned char nb[L_];
  __shared__ signed char tbl[128][4];
  __shared__ int st_in[128];
  __shared__ int offs[257];

  const int b = blockIdx.x, t = threadIdx.x;
  const int wv = t >> 6, lane = t & 63;
  const float* s = signal + b * L_;
  const unsigned int* hb = hist16 + ((unsigned)b << 16);

  float val[8];
  unsigned int key[8];
#pragma unroll
  for (int i = 0; i < 8; ++i) {
    val[i] = s[(i << 10) + t];
    const unsigned int u = __float_as_uint(val[i]);
    key[i] = (u & 0x80000000u) ? ~u : (u | 0x80000000u);
  }

  // ---- rounds 0+1 from hist16: thread t owns 16-bit bins [t*64, t*64+64) ----
  // transposed layout: bin (t*64+i) lives at hb[(i<<10)|t] -> coalesced.
  unsigned int tsum = 0;
#pragma unroll 8
  for (int i = 0; i < 64; ++i) tsum += hb[(i << 10) | t];
  {
    // block-wide inclusive scan of 1024 tsums
    unsigned int run = tsum;
#pragma unroll
    for (int off = 1; off < 64; off <<= 1) {
      const unsigned int v = __shfl_up(run, off, 64);
      if (lane >= off) run += v;
    }
    if (lane == 63) wpart[wv] = run;
    __syncthreads();
    unsigned int wadd = 0;
    for (int g = 0; g < wv; ++g) wadd += wpart[g];
    run += wadd;
    const unsigned int excl = run - tsum;
    const int r = 5733;                // rank = floor(0.7*(L-1))
    if (r >= (int)excl && r < (int)run) { sel_tt = t; sel_rr = r - (int)excl; }
    __syncthreads();
    if (t < 64) {
      const int tt = sel_tt, rr = sel_rr;
      const unsigned int cnt = hb[(t << 10) | tt];
      unsigned int irun = cnt;
#pragma unroll
      for (int off = 1; off < 64; off <<= 1) {
        const unsigned int v = __shfl_up(irun, off, 64);
        if (t >= off) irun += v;
      }
      const unsigned int iexcl = irun - cnt;
      if (rr >= (int)iexcl && rr < (int)irun) {
        sel_prefix = ((unsigned int)tt << 6) | (unsigned int)t;  // 16-bit prefix
        sel_rank   = rr - (int)iexcl;
      }
    }
    __syncthreads();
  }

  // ---- radix rounds 2..3 ----
  for (int round = 2; round < 4; ++round) {
    reinterpret_cast<unsigned int*>(bins)[t] = 0u;
    __syncthreads();
    const unsigned int pre = sel_prefix;
    const int shift = 24 - 8 * round;
#pragma unroll
    for (int i = 0; i < 8; ++i) {
      if ((key[i] >> (shift + 8)) == pre)
        atomicAdd(&bins[t >> 8][(key[i] >> shift) & 255u], 1u);
    }
    __syncthreads();
    if (t < 256)
      bins[0][t] = bins[0][t] + bins[1][t] + bins[2][t] + bins[3][t];
    __syncthreads();
    if (t < 64) {
      const unsigned int c0 = bins[0][(t << 2) + 0], c1 = bins[0][(t << 2) + 1];
      const unsigned int c2 = bins[0][(t << 2) + 2], c3 = bins[0][(t << 2) + 3];
      const unsigned int lsum = c0 + c1 + c2 + c3;
      unsigned int run = lsum;
#pragma unroll
      for (int off = 1; off < 64; off <<= 1) {
        const unsigned int v = __shfl_up(run, off, 64);
        if (t >= off) run += v;
      }
      const int r = sel_rank;
      if (r >= (int)(run - lsum) && r < (int)run) {
        int rr = r - (int)(run - lsum);
        unsigned int cbin;
        if (rr < (int)c0) { cbin = 0; }
        else if (rr < (int)(c0 + c1)) { cbin = 1; rr -= (int)c0; }
        else if (rr < (int)(c0 + c1 + c2)) { cbin = 2; rr -= (int)(c0 + c1); }
        else { cbin = 3; rr -= (int)(c0 + c1 + c2); }
        sel_rank = rr;
        sel_prefix = (pre << 8) | ((unsigned int)(t << 2) | cbin);
      }
    }
    __syncthreads();
  }
  const unsigned int k0 = sel_prefix;

  // ---- successor: count <=k0 and min of keys > k0 (tie-safe) ----
  {
    int cle = 0;
    unsigned int mgt = 0xFFFFFFFFu;
#pragma unroll
    for (int i = 0; i < 8; ++i) {
      if (key[i] <= k0) ++cle;
      else mgt = min(mgt, key[i]);
    }
#pragma unroll
    for (int off = 1; off < 64; off <<= 1) {
      cle += __shfl_xor(cle, off, 64);
      mgt = min(mgt, (unsigned int)__shfl_xor((int)mgt, off, 64));
    }
    if (lane == 0) { wcnt[wv] = cle; wmin[wv] = mgt; }
    __syncthreads();
    if (t == 0) {
      int C = 0; unsigned int M = 0xFFFFFFFFu;
      for (int g = 0; g < 16; ++g) { C += wcnt[g]; M = min(M, wmin[g]); }
      const unsigned int k1 = (C >= 5735) ? k0 : M;
      const unsigned int u0 = (k0 & 0x80000000u) ? (k0 & 0x7fffffffu) : ~k0;
      const unsigned int u1 = (k1 & 0x80000000u) ? (k1 & 0x7fffffffu) : ~k1;
      const float v0 = __uint_as_float(u0);
      const float v1 = __uint_as_float(u1);
      const float g = 0.7f * 8191.0f - 5733.0f;
      sh_thr = v0 + g * (v1 - v0);
    }
    __syncthreads();
  }
  const float thr = sh_thr;

  // ---- candidate bitmap from register values ----
#pragma unroll
  for (int i = 0; i < 8; ++i) {
    const unsigned long long m = __ballot(val[i] < thr);
    if (lane == 0) cw[(i << 4) + wv] = m;
  }
  {
    const int base = t << 3;
#pragma unroll
    for (int i = 0; i < 8; ++i) nb[base + i] = 0;
  }
  __syncthreads();
  if (t == 0) cw[127] |= (1ull << 63);   // forced candidate at L-1
  __syncthreads();

  // ---- (1) per-64-block transition tables ----
  if (t < 512) {
    const int blk = t >> 2, cls = t & 3;
    tbl[blk][cls] = (signed char)chain_sim(cw[blk], cls);
  }
  __syncthreads();

  // ---- (2) serial 128-step state scan ----
  if (t == 0) {
    int st = 0;
    for (int blk = 0; blk < 128; ++blk) {
      const int bs = blk << 6;
      st_in[blk] = st;
      int pl;
      if (blk == 0) {
        pl = chain_sim(cw[0], 4);
      } else {
        int off = st + 4 - bs;
        if (off < 0) off = 0;
        pl = tbl[blk][off];
      }
      if (pl >= 0) st = bs + pl;
    }
  }
  __syncthreads();

  // ---- (3) parallel emission of acceptance + split bytes ----
  if (t < 128) {
    const int bs = t << 6;
    const unsigned long long w = cw[t];
    int st = st_in[t];
    int from = st + 4 - bs;
    if (from < 0) from = 0;
    while (from < 64) {
      const unsigned long long m = w & (~0ull << from);
      if (m == 0ull) break;
      const int p_rel = __ffsll(m) - 1;
      const int p = bs + p_rel;
      nb[p] = 1;
      const int ps = p - st;
      const int k = (ps + 15) >> 4;
      if (k > 1) {
        int sz = ps / k; if (sz < 1) sz = 1;
        for (int j = 1; j < k; ++j) nb[st + j * sz] = 1;
      }
      st = p;
      from = p_rel + 4;
    }
  }
  __syncthreads();

  // ---- wave-parallel prefix scan over 256 x 32-token sums ----
  int ls = 0, run2 = 0;
  if (t < 256) {
    const int base = t << 5;
    for (int i = 0; i < 32; ++i) ls += nb[base + i];
    run2 = ls;
#pragma unroll
    for (int off = 1; off < 64; off <<= 1) {
      const int v = __shfl_up(run2, off, 64);
      if ((t & 63) >= off) run2 += v;
    }
    if ((t & 63) == 63) wcnt[t >> 6] = run2;   // reuse wcnt as wave partials
  }
  __syncthreads();
  if (t < 256) {
    const int w = t >> 6;
    int addb = 0;
    if (w > 0) addb += wcnt[0];
    if (w > 1) addb += wcnt[1];
    if (w > 2) addb += wcnt[2];
    offs[t] = addb + run2 - ls;               // exclusive prefix
    if (t == 255) offs[256] = addb + run2;
  }
  __syncthreads();
  if (t < 256) {
    const int base = t << 5;
    int rn = offs[t];
    for (int i = 0; i < 32; ++i) {
      rn += nb[base + i];
      if (nb[base + i]) starts[b * L_ + rn] = base + i;
    }
  }
  if (t == 0) { starts[b * L_ + 0] = 0; nlast[b] = offs[256]; }
}

// ---------------------------------------------------------------------------
// Segment softmax-merge: live sids only (merged/bounds pre-zeroed by
// k_signal). Dead sids exit after one nlast read.
// ---------------------------------------------------------------------------
__global__ __launch_bounds__(256) void k_merge(const float* __restrict__ x,
    const float* __restrict__ mask, const float* __restrict__ e,
    const int* __restrict__ starts, const int* __restrict__ nlast,
    float* __restrict__ merged, float* __restrict__ bounds)
{
  const int idx = (blockIdx.x << 2) + (threadIdx.x >> 6);
  const int b   = idx >> 13;
  const int sid = idx & (L_ - 1);
  const int n = nlast[b];
  if (sid > n) return;                 // merged row and bounds already zero
  const int lane = threadIdx.x & 63;
  if (lane == 0 && sid >= 1)
    bounds[(size_t)b * L_ + sid] = 1.0f;
  const int c0 = lane << 3;
  float* o = merged + (size_t)(b * L_ + sid) * D_ + c0;
  const int t0 = starts[b * L_ + sid];
  const int t1 = (sid < n) ? starts[b * L_ + sid + 1] : L_;
  const int len = t1 - t0;
  const float* eb = e + b * L_;

  float acc[8] = {0,0,0,0,0,0,0,0};

  if (len <= 64) {
    // ---- whole segment in-wave: 1 coalesced e load + shfl reductions ----
    const float ev = (lane < len) ? eb[t0 + lane] : -INFINITY;
    float mx = ev;
#pragma unroll
    for (int off = 1; off < 64; off <<= 1)
      mx = fmaxf(mx, __shfl_xor(mx, off, 64));
    const float ex = expf(ev - mx);          // 0 for dead lanes
    float den = ex;
#pragma unroll
    for (int off = 1; off < 64; off <<= 1)
      den += __shfl_xor(den, off, 64);
    const float mk = (lane < len) ? mask[b * L_ + t0 + lane] : 0.f;
    const float scl = (ex / den) * mk;       // per-lane: weight of row t0+lane

    // ---- x-row loop with 2-deep load pipeline ----
    const float* xr = x + (size_t)(b * L_ + t0) * D_ + c0;
    float4 u0 = reinterpret_cast<const float4*>(xr)[0];
    float4 u1 = reinterpret_cast<const float4*>(xr)[1];
    for (int r = 0; r < len; ++r) {
      float4 n0, n1;
      if (r + 1 < len) {
        const float* xn = xr + (size_t)(r + 1) * D_;
        n0 = reinterpret_cast<const float4*>(xn)[0];
        n1 = reinterpret_cast<const float4*>(xn)[1];
      }
      const float sc = __shfl(scl, r, 64);
      acc[0] = fmaf(sc, u0.x, acc[0]); acc[1] = fmaf(sc, u0.y, acc[1]);
      acc[2] = fmaf(sc, u0.z, acc[2]); acc[3] = fmaf(sc, u0.w, acc[3]);
      acc[4] = fmaf(sc, u1.x, acc[4]); acc[5] = fmaf(sc, u1.y, acc[5]);
      acc[6] = fmaf(sc, u1.z, acc[6]); acc[7] = fmaf(sc, u1.w, acc[7]);
      u0 = n0; u1 = n1;
    }
  } else {
    // ---- fallback (len > 64): original serial path ----
    float mx = -INFINITY;
    for (int p = t0; p < t1; ++p) mx = fmaxf(mx, eb[p]);
    float den = 0.f;
    for (int p = t0; p < t1; ++p) den += expf(eb[p] - mx);
    for (int p = t0; p < t1; ++p) {
      const float wn = expf(eb[p] - mx) / den;
      const float sc = wn * mask[b * L_ + p];
      const float* xr = x + ((size_t)(b * L_ + p)) * D_ + c0;
      const float4 u0 = reinterpret_cast<const float4*>(xr)[0];
      const float4 u1 = reinterpret_cast<const float4*>(xr)[1];
      acc[0] = fmaf(sc, u0.x, acc[0]); acc[1] = fmaf(sc, u0.y, acc[1]);
      acc[2] = fmaf(sc, u0.z, acc[2]); acc[3] = fmaf(sc, u0.w, acc[3]);
      acc[4] = fmaf(sc, u1.x, acc[4]); acc[5] = fmaf(sc, u1.y, acc[5]);
      acc[6] = fmaf(sc, u1.z, acc[6]); acc[7] = fmaf(sc, u1.w, acc[7]);
    }
  }
  reinterpret_cast<float4*>(o)[0] = make_float4(acc[0], acc[1], acc[2], acc[3]);
  reinterpret_cast<float4*>(o)[1] = make_float4(acc[4], acc[5], acc[6], acc[7]);
}

// ---------------------------------------------------------------------------
extern "C" void kernel_launch(void* const* d_in, const int* in_sizes, int n_in,
                              void* d_out, int out_size, void* d_ws, size_t ws_size,
                              hipStream_t stream) {
  (void)in_sizes; (void)n_in; (void)out_size; (void)ws_size;
  const float* x    = (const float*)d_in[0];
  const float* mask = (const float*)d_in[1];
  const float* W1   = (const float*)d_in[2];
  const float* b1   = (const float*)d_in[3];
  const float* W2   = (const float*)d_in[4];
  const float* b2   = (const float*)d_in[5];
  const float* Wc   = (const float*)d_in[6];
  const float* bc   = (const float*)d_in[7];
  const float* Wb1  = (const float*)d_in[8];
  const float* bb1  = (const float*)d_in[9];
  const float* Wb2  = (const float*)d_in[10];
  const float* bb2  = (const float*)d_in[11];

  float* merged = (float*)d_out;
  float* bounds = (float*)d_out + (size_t)BL_ * D_;

  char* ws = (char*)d_ws;
  float*        signal = (float*)(ws);
  float*        e      = (float*)(ws + (size_t)BL_ * 4);
  int*          starts = (int*)  (ws + (size_t)BL_ * 8);
  int*          nlast  = (int*)  (ws + (size_t)BL_ * 12);
  unsigned int* hist16 = (unsigned int*)(ws + (size_t)BL_ * 12 + 1024);

  hipMemsetAsync(hist16, 0, (size_t)B_ * 65536 * sizeof(unsigned int), stream);
  k_signal<<<BL_ / TOK, 256, 0, stream>>>(x, mask, W1, b1, W2, b2, Wc, bc,
                                          Wb1, bb1, Wb2, bb2, signal, e,
                                          hist16, merged, bounds);
  k_select<<<B_, 1024, 0, stream>>>(signal, hist16, starts, nlast);
  k_merge<<<BL_ / 4, 256, 0, stream>>>(x, mask, e, starts, nlast, merged, bounds);
}

// Round 10
// 291.790 us; speedup vs baseline: 1.0795x; 1.0011x over previous
//
#include <hip/hip_runtime.h>
#include <math.h>

#define B_  4
#define L_  8192
#define D_  512
#define BL_ (B_*L_)
#define TOK 64
#define XS  68            // 64 tok + 2 halo + 2 pad
#define KC  16
#define NCH (D_/KC)

// ---------------------------------------------------------------------------
// Signal + e — R1 core + riders (measured 170us): merged/bounds zeroing and
// the 16-bit signal histogram (skips radix rounds 0-1 in k_select).
// Numerics bit-identical to R7/R8/R9.
// ---------------------------------------------------------------------------
__global__ __launch_bounds__(256, 2) void k_signal(
    const float* __restrict__ x, const float* __restrict__ mask,
    const float* __restrict__ W1, const float* __restrict__ b1,
    const float* __restrict__ W2, const float* __restrict__ b2,
    const float* __restrict__ Wc, const float* __restrict__ bc,
    const float* __restrict__ Wb1, const float* __restrict__ bb1,
    const float* __restrict__ Wb2, const float* __restrict__ bb2,
    float* __restrict__ signal, float* __restrict__ e,
    unsigned int* __restrict__ hist16,
    float* __restrict__ merged, float* __restrict__ bounds)
{
  __shared__ float ws1[KC][128];   // W1 chunk rows kc..kc+15
  __shared__ float wsb[KC][128];   // Wb1 x-part chunk
  __shared__ float wsp[8][128];    // Wb1 pf-part chunk (8 conv channels/chunk)
  __shared__ float xt[KC][XS];     // x transposed; col 64 = l0-1, 65 = l0+64
  __shared__ float pf[8][XS];      // conv out chunk

  const int t   = threadIdx.x;
  const int blk = blockIdx.x;          // 512 = 4 b x 128 tiles
  const int b   = blk >> 7;
  const int l0  = (blk & 127) << 6;
  const float* xb = x + (size_t)b * L_ * D_;

  const int jq = t & 31, tw = t >> 5;
  const int j0 = jq << 2, tok0 = tw << 3;

  // x-staging / e role: all 256 threads, one float4 per chunk
  const int stok = t >> 2, skk = t & 3;
  // conv role: out-ch oo_c, adjacent token pair (m2, m2+1)
  const int oo_c = t >> 5;             // 0..7
  const int m2   = (t & 31) << 1;      // 0,2,...,62
  const int cb_c = (oo_c >> 1) << 2;   // rel in-channel base {0,4,8,12}

  const int srow = t >> 5, sc4 = (t & 31) << 2;

  // ---- bounds zeroing for this block's 64 sids (once, fire-and-forget) ----
  if (t < 16) {
    float4* bz = reinterpret_cast<float4*>(bounds + (size_t)b * L_ + l0);
    bz[t] = make_float4(0.f, 0.f, 0.f, 0.f);
  }
  float4* mz = reinterpret_cast<float4*>(merged + (size_t)(b * L_ + l0) * D_);

  float a1[8][4], a2[8][4];
#pragma unroll
  for (int i = 0; i < 8; ++i)
#pragma unroll
    for (int j = 0; j < 4; ++j) { a1[i][j] = 0.f; a2[i][j] = 0.f; }
  float esacc = 0.f;

  // prefetch registers (next chunk)
  float4 r_w1a, r_w1b, r_wba, r_wbb, r_wp, r_xv, r_hv;
  float4 r_wc0, r_wc1, r_wc2;
  float  r_bc;

  auto LOAD = [&](int c) {
    const int kc = c << 4;
    r_w1a = *reinterpret_cast<const float4*>(W1  + (size_t)(kc + srow) * 128 + sc4);
    r_w1b = *reinterpret_cast<const float4*>(W1  + (size_t)(kc + 8 + srow) * 128 + sc4);
    r_wba = *reinterpret_cast<const float4*>(Wb1 + (size_t)(kc + srow) * 128 + sc4);
    r_wbb = *reinterpret_cast<const float4*>(Wb1 + (size_t)(kc + 8 + srow) * 128 + sc4);
    r_wp  = *reinterpret_cast<const float4*>(Wb1 + (size_t)(512 + (c << 3) + srow) * 128 + sc4);
    r_xv  = *reinterpret_cast<const float4*>(xb + (size_t)(l0 + stok) * D_ + kc + (skk << 2));
    if (t < 8) {
      const int hh = t >> 2, kk = t & 3;
      const int l = hh ? (l0 + TOK) : (l0 - 1);
      r_hv = make_float4(0.f, 0.f, 0.f, 0.f);
      if (l >= 0 && l < L_)
        r_hv = *reinterpret_cast<const float4*>(xb + (size_t)l * D_ + kc + (kk << 2));
    }
    const int o = (c << 3) + oo_c;
    const float* wcp = Wc + o * 12;
    r_wc0 = *reinterpret_cast<const float4*>(wcp);
    r_wc1 = *reinterpret_cast<const float4*>(wcp + 4);
    r_wc2 = *reinterpret_cast<const float4*>(wcp + 8);
    r_bc  = bc[o];
  };

  LOAD(0);

  for (int c = 0; c < NCH; ++c) {
    __syncthreads();                   // previous chunk fully consumed

    // ---- write staged registers into LDS ----
    *reinterpret_cast<float4*>(&ws1[srow][sc4])     = r_w1a;
    *reinterpret_cast<float4*>(&ws1[8 + srow][sc4]) = r_w1b;
    *reinterpret_cast<float4*>(&wsb[srow][sc4])     = r_wba;
    *reinterpret_cast<float4*>(&wsb[8 + srow][sc4]) = r_wbb;
    *reinterpret_cast<float4*>(&wsp[srow][sc4])     = r_wp;
    {
      const float4 v = r_xv;
      esacc = fmaf(v.x, v.x, esacc); esacc = fmaf(v.y, v.y, esacc);
      esacc = fmaf(v.z, v.z, esacc); esacc = fmaf(v.w, v.w, esacc);
      const int r = skk << 2;
      xt[r + 0][stok] = v.x; xt[r + 1][stok] = v.y;
      xt[r + 2][stok] = v.z; xt[r + 3][stok] = v.w;
    }
    if (t < 8) {
      const int hh = t >> 2, kk = t & 3;
      const int col = TOK + hh, r = kk << 2;
      xt[r + 0][col] = r_hv.x; xt[r + 1][col] = r_hv.y;
      xt[r + 2][col] = r_hv.z; xt[r + 3][col] = r_hv.w;
    }
    __syncthreads();                   // staged data visible

    // keep this chunk's conv weights before the prefetch overwrites them
    float wcl[12];
    wcl[0] = r_wc0.x; wcl[1]  = r_wc0.y; wcl[2]  = r_wc0.z; wcl[3]  = r_wc0.w;
    wcl[4] = r_wc1.x; wcl[5]  = r_wc1.y; wcl[6]  = r_wc1.z; wcl[7]  = r_wc1.w;
    wcl[8] = r_wc2.x; wcl[9]  = r_wc2.y; wcl[10] = r_wc2.z; wcl[11] = r_wc2.w;
    const float bcv = r_bc;

    if (c + 1 < NCH) LOAD(c + 1);      // issue next chunk's global loads

    // ---- merged-zero rider: 1 float4/thread/chunk, drains under compute ----
    mz[(c << 8) + t] = make_float4(0.f, 0.f, 0.f, 0.f);

    // ---- conv: out-ch (c*8+oo_c), tokens m2 and m2+1 ----
    {
      float pa = bcv, pb = bcv;
      const int tm1 = (m2 == 0) ? TOK : m2 - 1;
      const int tp2 = (m2 + 2 == TOK) ? TOK + 1 : m2 + 2;
#pragma unroll
      for (int i = 0; i < 4; ++i) {
        const float* row = &xt[cb_c + i][0];
        const float  xm1 = row[tm1];
        const float2 x01 = *reinterpret_cast<const float2*>(&row[m2]);
        const float  xp2 = row[tp2];
        pa = fmaf(xm1,   wcl[i * 3 + 0], pa);
        pa = fmaf(x01.x, wcl[i * 3 + 1], pa);
        pa = fmaf(x01.y, wcl[i * 3 + 2], pa);
        pb = fmaf(x01.x, wcl[i * 3 + 0], pb);
        pb = fmaf(x01.y, wcl[i * 3 + 1], pb);
        pb = fmaf(xp2,   wcl[i * 3 + 2], pb);
      }
      *reinterpret_cast<float2*>(&pf[oo_c][m2]) = make_float2(pa, pb);
    }

    // ---- GEMM x-part: 4 b128 -> 64 FMA per k ----
#pragma unroll 4
    for (int k = 0; k < KC; ++k) {
      const float4 w1 = *reinterpret_cast<const float4*>(&ws1[k][j0]);
      const float4 wb = *reinterpret_cast<const float4*>(&wsb[k][j0]);
      const float4 xa = *reinterpret_cast<const float4*>(&xt[k][tok0]);
      const float4 xc = *reinterpret_cast<const float4*>(&xt[k][tok0 + 4]);
      const float xs8[8] = {xa.x, xa.y, xa.z, xa.w, xc.x, xc.y, xc.z, xc.w};
#pragma unroll
      for (int i = 0; i < 8; ++i) {
        a1[i][0] = fmaf(xs8[i], w1.x, a1[i][0]);
        a1[i][1] = fmaf(xs8[i], w1.y, a1[i][1]);
        a1[i][2] = fmaf(xs8[i], w1.z, a1[i][2]);
        a1[i][3] = fmaf(xs8[i], w1.w, a1[i][3]);
        a2[i][0] = fmaf(xs8[i], wb.x, a2[i][0]);
        a2[i][1] = fmaf(xs8[i], wb.y, a2[i][1]);
        a2[i][2] = fmaf(xs8[i], wb.z, a2[i][2]);
        a2[i][3] = fmaf(xs8[i], wb.w, a2[i][3]);
      }
    }
    __syncthreads();                   // pf writes visible

    // ---- GEMM pf-part ----
#pragma unroll 2
    for (int oo = 0; oo < 8; ++oo) {
      const float4 wp = *reinterpret_cast<const float4*>(&wsp[oo][j0]);
      const float4 pa4 = *reinterpret_cast<const float4*>(&pf[oo][tok0]);
      const float4 pb4 = *reinterpret_cast<const float4*>(&pf[oo][tok0 + 4]);
      const float ps8[8] = {pa4.x, pa4.y, pa4.z, pa4.w, pb4.x, pb4.y, pb4.z, pb4.w};
#pragma unroll
      for (int i = 0; i < 8; ++i) {
        a2[i][0] = fmaf(ps8[i], wp.x, a2[i][0]);
        a2[i][1] = fmaf(ps8[i], wp.y, a2[i][1]);
        a2[i][2] = fmaf(ps8[i], wp.z, a2[i][2]);
        a2[i][3] = fmaf(ps8[i], wp.w, a2[i][3]);
      }
    }
  }

  // ---- epilogue: relu, project, cross-jq reduce, sigmoid, hist16 ----
  {
    float b1v[4], w2v[4], bbv[4], wv2[4];
#pragma unroll
    for (int jj = 0; jj < 4; ++jj) {
      b1v[jj] = b1[j0 + jj];  w2v[jj] = W2[j0 + jj];
      bbv[jj] = bb1[j0 + jj]; wv2[jj] = Wb2[j0 + jj];
    }
    const float bias2 = b2[0], biasb2 = bb2[0];
#pragma unroll
    for (int i = 0; i < 8; ++i) {
      float p1 = 0.f, p2 = 0.f;
#pragma unroll
      for (int jj = 0; jj < 4; ++jj) {
        const float h1 = a1[i][jj] + b1v[jj];
        if (h1 > 0.f) p1 = fmaf(h1, w2v[jj], p1);
        const float h2 = a2[i][jj] + bbv[jj];
        if (h2 > 0.f) p2 = fmaf(h2, wv2[jj], p2);
      }
#pragma unroll
      for (int off = 1; off < 32; off <<= 1) {
        p1 += __shfl_xor(p1, off, 64);
        p2 += __shfl_xor(p2, off, 64);
      }
      if (jq == 0) {
        const int gi = b * L_ + l0 + tok0 + i;
        const float content = 1.f / (1.f + expf(-(p1 + bias2)));
        const float bscore  = 1.f / (1.f + expf(-(p2 + biasb2)));
        const float s = content * (1.f - bscore) * mask[gi];
        signal[gi] = s;
        const unsigned int u = __float_as_uint(s);
        const unsigned int key = (u & 0x80000000u) ? ~u : (u | 0x80000000u);
        const unsigned int bb16 = key >> 16;
        // transposed bin layout: loc = (bb&63)*1024 + (bb>>6)  (coalesced scan)
        atomicAdd(&hist16[((unsigned)b << 16) | ((bb16 & 63u) << 10) | (bb16 >> 6)], 1u);
      }
    }
  }

  // ---- e epilogue: reduce over the 4 skk lanes of each token ----
  {
    float es = esacc;
    es += __shfl_xor(es, 1, 64);
    es += __shfl_xor(es, 2, 64);
    if (skk == 0) {
      const int gi = b * L_ + l0 + stok;
      const float m = mask[gi];
      e[gi] = m * m * es;
    }
  }
}

// ---------------------------------------------------------------------------
// Fused quantile + enforce. One block (1024 thr) per batch row.
// Rounds 0-1 from the k_signal-built 16-bit histogram; the serial 128-step
// enforce-state scan is replaced by an EXACT parallel function-composition
// scan: each block's transition is a 4-entry map (entering-class 0..3 ->
// absolute last-accept or PASS), packed 4x16b in a u64 and composed with
// shfl_up in 6 steps + one cross-wave splice. Left-PASS composes to right
// class 0 (a passed-through state is >=64 positions stale).
// ---------------------------------------------------------------------------
__device__ __forceinline__ int chain_sim(unsigned long long w, int from) {
  int last = -1;
  while (from < 64) {
    const unsigned long long m = w & (~0ull << from);
    if (m == 0ull) break;
    const int p = __ffsll(m) - 1;
    last = p;
    from = p + 4;
  }
  return last;
}

__device__ __forceinline__ unsigned long long compose_fn(
    unsigned long long g, unsigned long long f, int lobase) {
  // g covers left block range; f covers right range starting at block lobase
  unsigned long long h = 0ull;
  const int bs = lobase << 6;
#pragma unroll
  for (int c = 0; c < 4; ++c) {
    const unsigned int p = (unsigned int)((g >> (c * 16)) & 0xFFFFu);
    unsigned int q;
    if (p == 0xFFFFu) {
      q = (unsigned int)(f & 0xFFFFu);               // right sees class 0
    } else {
      int cls2 = (int)p + 4 - bs; if (cls2 < 0) cls2 = 0;   // <=3 guaranteed
      const unsigned int r = (unsigned int)((f >> (cls2 * 16)) & 0xFFFFu);
      q = (r == 0xFFFFu) ? p : r;
    }
    h |= (unsigned long long)q << (c * 16);
  }
  return h;
}

__global__ __launch_bounds__(1024) void k_select(
    const float* __restrict__ signal, const unsigned int* __restrict__ hist16,
    int* __restrict__ starts, int* __restrict__ nlast)
{
  __shared__ unsigned int bins[4][256];
  __shared__ unsigned int sel_prefix;
  __shared__ int sel_rank;
  __shared__ int sel_tt, sel_rr;
  __shared__ unsigned int wpart[16];
  __shared__ float sh_thr;
  __shared__ unsigned int wmin[16];
  __shared__ int wcnt[16];
  __shared__ unsigned long long cw[128];
  __shared__ unsigned long long sh_w0;
  __shared__ unsigned char nb[L_];
  __shared__ signed char tbl[128][4];
  __shared__ int st_in[128];
  __shared__ int offs[257];

  const int b = blockIdx.x, t = threadIdx.x;
  const int wv = t >> 6, lane = t & 63;
  const float* s = signal + b * L_;
  const unsigned int* hb = hist16 + ((unsigned)b << 16);

  float val[8];
  unsigned int key[8];
#pragma unroll
  for (int i = 0; i < 8; ++i) {
    val[i] = s[(i << 10) + t];
    const unsigned int u = __float_as_uint(val[i]);
    key[i] = (u & 0x80000000u) ? ~u : (u | 0x80000000u);
  }

  // ---- rounds 0+1 from hist16: thread t owns 16-bit bins [t*64, t*64+64) ----
  unsigned int tsum = 0;
#pragma unroll 8
  for (int i = 0; i < 64; ++i) tsum += hb[(i << 10) | t];
  {
    unsigned int run = tsum;
#pragma unroll
    for (int off = 1; off < 64; off <<= 1) {
      const unsigned int v = __shfl_up(run, off, 64);
      if (lane >= off) run += v;
    }
    if (lane == 63) wpart[wv] = run;
    __syncthreads();
    unsigned int wadd = 0;
    for (int g = 0; g < wv; ++g) wadd += wpart[g];
    run += wadd;
    const unsigned int excl = run - tsum;
    const int r = 5733;                // rank = floor(0.7*(L-1))
    if (r >= (int)excl && r < (int)run) { sel_tt = t; sel_rr = r - (int)excl; }
    __syncthreads();
    if (t < 64) {
      const int tt = sel_tt, rr = sel_rr;
      const unsigned int cnt = hb[(t << 10) | tt];
      unsigned int irun = cnt;
#pragma unroll
      for (int off = 1; off < 64; off <<= 1) {
        const unsigned int v = __shfl_up(irun, off, 64);
        if (t >= off) irun += v;
      }
      const unsigned int iexcl = irun - cnt;
      if (rr >= (int)iexcl && rr < (int)irun) {
        sel_prefix = ((unsigned int)tt << 6) | (unsigned int)t;  // 16-bit prefix
        sel_rank   = rr - (int)iexcl;
      }
    }
    __syncthreads();
  }

  // ---- radix rounds 2..3 ----
  for (int round = 2; round < 4; ++round) {
    reinterpret_cast<unsigned int*>(bins)[t] = 0u;
    __syncthreads();
    const unsigned int pre = sel_prefix;
    const int shift = 24 - 8 * round;
#pragma unroll
    for (int i = 0; i < 8; ++i) {
      if ((key[i] >> (shift + 8)) == pre)
        atomicAdd(&bins[t >> 8][(key[i] >> shift) & 255u], 1u);
    }
    __syncthreads();
    if (t < 256)
      bins[0][t] = bins[0][t] + bins[1][t] + bins[2][t] + bins[3][t];
    __syncthreads();
    if (t < 64) {
      const unsigned int c0 = bins[0][(t << 2) + 0], c1 = bins[0][(t << 2) + 1];
      const unsigned int c2 = bins[0][(t << 2) + 2], c3 = bins[0][(t << 2) + 3];
      const unsigned int lsum = c0 + c1 + c2 + c3;
      unsigned int run = lsum;
#pragma unroll
      for (int off = 1; off < 64; off <<= 1) {
        const unsigned int v = __shfl_up(run, off, 64);
        if (t >= off) run += v;
      }
      const int r = sel_rank;
      if (r >= (int)(run - lsum) && r < (int)run) {
        int rr = r - (int)(run - lsum);
        unsigned int cbin;
        if (rr < (int)c0) { cbin = 0; }
        else if (rr < (int)(c0 + c1)) { cbin = 1; rr -= (int)c0; }
        else if (rr < (int)(c0 + c1 + c2)) { cbin = 2; rr -= (int)(c0 + c1); }
        else { cbin = 3; rr -= (int)(c0 + c1 + c2); }
        sel_rank = rr;
        sel_prefix = (pre << 8) | ((unsigned int)(t << 2) | cbin);
      }
    }
    __syncthreads();
  }
  const unsigned int k0 = sel_prefix;

  // ---- successor: count <=k0 and min of keys > k0 (tie-safe) ----
  {
    int cle = 0;
    unsigned int mgt = 0xFFFFFFFFu;
#pragma unroll
    for (int i = 0; i < 8; ++i) {
      if (key[i] <= k0) ++cle;
      else mgt = min(mgt, key[i]);
    }
#pragma unroll
    for (int off = 1; off < 64; off <<= 1) {
      cle += __shfl_xor(cle, off, 64);
      mgt = min(mgt, (unsigned int)__shfl_xor((int)mgt, off, 64));
    }
    if (lane == 0) { wcnt[wv] = cle; wmin[wv] = mgt; }
    __syncthreads();
    if (t == 0) {
      int C = 0; unsigned int M = 0xFFFFFFFFu;
      for (int g = 0; g < 16; ++g) { C += wcnt[g]; M = min(M, wmin[g]); }
      const unsigned int k1 = (C >= 5735) ? k0 : M;
      const unsigned int u0 = (k0 & 0x80000000u) ? (k0 & 0x7fffffffu) : ~k0;
      const unsigned int u1 = (k1 & 0x80000000u) ? (k1 & 0x7fffffffu) : ~k1;
      const float v0 = __uint_as_float(u0);
      const float v1 = __uint_as_float(u1);
      const float g = 0.7f * 8191.0f - 5733.0f;
      sh_thr = v0 + g * (v1 - v0);
    }
    __syncthreads();
  }
  const float thr = sh_thr;

  // ---- candidate bitmap from register values ----
#pragma unroll
  for (int i = 0; i < 8; ++i) {
    const unsigned long long m = __ballot(val[i] < thr);
    if (lane == 0) cw[(i << 4) + wv] = m;
  }
  {
    const int base = t << 3;
#pragma unroll
    for (int i = 0; i < 8; ++i) nb[base + i] = 0;
  }
  __syncthreads();
  if (t == 0) cw[127] |= (1ull << 63);   // forced candidate at L-1
  __syncthreads();

  // ---- (1) per-64-block transition tables ----
  if (t < 512) {
    const int blk = t >> 2, cls = t & 3;
    tbl[blk][cls] = (signed char)chain_sim(cw[blk], cls);
  }
  __syncthreads();

  // ---- (2) parallel function-composition scan over 128 block transitions ----
  {
    unsigned long long ffn = 0ull;
    int lo = t;
    if (t < 128) {
      if (t == 0) {
        const int p = chain_sim(cw[0], 4);
        const unsigned long long e = (p >= 0) ? (unsigned long long)(unsigned int)p
                                              : 0xFFFFull;
        ffn = e | (e << 16) | (e << 32) | (e << 48);
      } else {
#pragma unroll
        for (int c = 0; c < 4; ++c) {
          const int p = tbl[t][c];
          const unsigned long long ent =
              (p >= 0) ? (unsigned long long)(unsigned int)((t << 6) + p)
                       : 0xFFFFull;
          ffn |= ent << (c * 16);
        }
      }
      const int l7 = t & 63;
#pragma unroll
      for (int off = 1; off < 64; off <<= 1) {
        const unsigned long long g = __shfl_up(ffn, off, 64);
        const int glo = __shfl_up(lo, off, 64);
        if (l7 >= off) { ffn = compose_fn(g, ffn, lo); lo = glo; }
      }
      if (t == 63) sh_w0 = ffn;
    }
    __syncthreads();
    if (t >= 64 && t < 128) ffn = compose_fn(sh_w0, ffn, lo);  // lo == 64 here
    if (t == 0) st_in[0] = 0;
    if (t < 127) {
      const unsigned int p = (unsigned int)(ffn & 0xFFFFu);
      st_in[t + 1] = (p == 0xFFFFu) ? 0 : (int)p;
    }
  }
  __syncthreads();

  // ---- (3) parallel emission of acceptance + split bytes ----
  if (t < 128) {
    const int bs = t << 6;
    const unsigned long long w = cw[t];
    int st = st_in[t];
    int from = st + 4 - bs;
    if (from < 0) from = 0;
    while (from < 64) {
      const unsigned long long m = w & (~0ull << from);
      if (m == 0ull) break;
      const int p_rel = __ffsll(m) - 1;
      const int p = bs + p_rel;
      nb[p] = 1;
      const int ps = p - st;
      const int k = (ps + 15) >> 4;
      if (k > 1) {
        int sz = ps / k; if (sz < 1) sz = 1;
        for (int j = 1; j < k; ++j) nb[st + j * sz] = 1;
      }
      st = p;
      from = p_rel + 4;
    }
  }
  __syncthreads();

  // ---- wave-parallel prefix scan over 256 x 32-token sums ----
  int ls = 0, run2 = 0;
  if (t < 256) {
    const int base = t << 5;
    for (int i = 0; i < 32; ++i) ls += nb[base + i];
    run2 = ls;
#pragma unroll
    for (int off = 1; off < 64; off <<= 1) {
      const int v = __shfl_up(run2, off, 64);
      if ((t & 63) >= off) run2 += v;
    }
    if ((t & 63) == 63) wcnt[t >> 6] = run2;   // reuse wcnt as wave partials
  }
  __syncthreads();
  if (t < 256) {
    const int w = t >> 6;
    int addb = 0;
    if (w > 0) addb += wcnt[0];
    if (w > 1) addb += wcnt[1];
    if (w > 2) addb += wcnt[2];
    offs[t] = addb + run2 - ls;               // exclusive prefix
    if (t == 255) offs[256] = addb + run2;
  }
  __syncthreads();
  if (t < 256) {
    const int base = t << 5;
    int rn = offs[t];
    for (int i = 0; i < 32; ++i) {
      rn += nb[base + i];
      if (nb[base + i]) starts[b * L_ + rn] = base + i;
    }
  }
  if (t == 0) { starts[b * L_ + 0] = 0; nlast[b] = offs[256]; }
}

// ---------------------------------------------------------------------------
// Segment softmax-merge: live sids only (merged/bounds pre-zeroed by
// k_signal). Dead sids exit after one nlast read.
// ---------------------------------------------------------------------------
__global__ __launch_bounds__(256) void k_merge(const float* __restrict__ x,
    const float* __restrict__ mask, const float* __restrict__ e,
    const int* __restrict__ starts, const int* __restrict__ nlast,
    float* __restrict__ merged, float* __restrict__ bounds)
{
  const int idx = (blockIdx.x << 2) + (threadIdx.x >> 6);
  const int b   = idx >> 13;
  const int sid = idx & (L_ - 1);
  const int n = nlast[b];
  if (sid > n) return;                 // merged row and bounds already zero
  const int lane = threadIdx.x & 63;
  if (lane == 0 && sid >= 1)
    bounds[(size_t)b * L_ + sid] = 1.0f;
  const int c0 = lane << 3;
  float* o = merged + (size_t)(b * L_ + sid) * D_ + c0;
  const int t0 = starts[b * L_ + sid];
  const int t1 = (sid < n) ? starts[b * L_ + sid + 1] : L_;
  const int len = t1 - t0;
  const float* eb = e + b * L_;

  float acc[8] = {0,0,0,0,0,0,0,0};

  if (len <= 64) {
    // ---- whole segment in-wave: 1 coalesced e load + shfl reductions ----
    const float ev = (lane < len) ? eb[t0 + lane] : -INFINITY;
    float mx = ev;
#pragma unroll
    for (int off = 1; off < 64; off <<= 1)
      mx = fmaxf(mx, __shfl_xor(mx, off, 64));
    const float ex = expf(ev - mx);          // 0 for dead lanes
    float den = ex;
#pragma unroll
    for (int off = 1; off < 64; off <<= 1)
      den += __shfl_xor(den, off, 64);
    const float mk = (lane < len) ? mask[b * L_ + t0 + lane] : 0.f;
    const float scl = (ex / den) * mk;       // per-lane: weight of row t0+lane

    // ---- x-row loop with 2-deep load pipeline ----
    const float* xr = x + (size_t)(b * L_ + t0) * D_ + c0;
    float4 u0 = reinterpret_cast<const float4*>(xr)[0];
    float4 u1 = reinterpret_cast<const float4*>(xr)[1];
    for (int r = 0; r < len; ++r) {
      float4 n0, n1;
      if (r + 1 < len) {
        const float* xn = xr + (size_t)(r + 1) * D_;
        n0 = reinterpret_cast<const float4*>(xn)[0];
        n1 = reinterpret_cast<const float4*>(xn)[1];
      }
      const float sc = __shfl(scl, r, 64);
      acc[0] = fmaf(sc, u0.x, acc[0]); acc[1] = fmaf(sc, u0.y, acc[1]);
      acc[2] = fmaf(sc, u0.z, acc[2]); acc[3] = fmaf(sc, u0.w, acc[3]);
      acc[4] = fmaf(sc, u1.x, acc[4]); acc[5] = fmaf(sc, u1.y, acc[5]);
      acc[6] = fmaf(sc, u1.z, acc[6]); acc[7] = fmaf(sc, u1.w, acc[7]);
      u0 = n0; u1 = n1;
    }
  } else {
    // ---- fallback (len > 64): original serial path ----
    float mx = -INFINITY;
    for (int p = t0; p < t1; ++p) mx = fmaxf(mx, eb[p]);
    float den = 0.f;
    for (int p = t0; p < t1; ++p) den += expf(eb[p] - mx);
    for (int p = t0; p < t1; ++p) {
      const float wn = expf(eb[p] - mx) / den;
      const float sc = wn * mask[b * L_ + p];
      const float* xr = x + ((size_t)(b * L_ + p)) * D_ + c0;
      const float4 u0 = reinterpret_cast<const float4*>(xr)[0];
      const float4 u1 = reinterpret_cast<const float4*>(xr)[1];
      acc[0] = fmaf(sc, u0.x, acc[0]); acc[1] = fmaf(sc, u0.y, acc[1]);
      acc[2] = fmaf(sc, u0.z, acc[2]); acc[3] = fmaf(sc, u0.w, acc[3]);
      acc[4] = fmaf(sc, u1.x, acc[4]); acc[5] = fmaf(sc, u1.y, acc[5]);
      acc[6] = fmaf(sc, u1.z, acc[6]); acc[7] = fmaf(sc, u1.w, acc[7]);
    }
  }
  reinterpret_cast<float4*>(o)[0] = make_float4(acc[0], acc[1], acc[2], acc[3]);
  reinterpret_cast<float4*>(o)[1] = make_float4(acc[4], acc[5], acc[6], acc[7]);
}

// ---------------------------------------------------------------------------
extern "C" void kernel_launch(void* const* d_in, const int* in_sizes, int n_in,
                              void* d_out, int out_size, void* d_ws, size_t ws_size,
                              hipStream_t stream) {
  (void)in_sizes; (void)n_in; (void)out_size; (void)ws_size;
  const float* x    = (const float*)d_in[0];
  const float* mask = (const float*)d_in[1];
  const float* W1   = (const float*)d_in[2];
  const float* b1   = (const float*)d_in[3];
  const float* W2   = (const float*)d_in[4];
  const float* b2   = (const float*)d_in[5];
  const float* Wc   = (const float*)d_in[6];
  const float* bc   = (const float*)d_in[7];
  const float* Wb1  = (const float*)d_in[8];
  const float* bb1  = (const float*)d_in[9];
  const float* Wb2  = (const float*)d_in[10];
  const float* bb2  = (const float*)d_in[11];

  float* merged = (float*)d_out;
  float* bounds = (float*)d_out + (size_t)BL_ * D_;

  char* ws = (char*)d_ws;
  float*        signal = (float*)(ws);
  float*        e      = (float*)(ws + (size_t)BL_ * 4);
  int*          starts = (int*)  (ws + (size_t)BL_ * 8);
  int*          nlast  = (int*)  (ws + (size_t)BL_ * 12);
  unsigned int* hist16 = (unsigned int*)(ws + (size_t)BL_ * 12 + 1024);

  hipMemsetAsync(hist16, 0, (size_t)B_ * 65536 * sizeof(unsigned int), stream);
  k_signal<<<BL_ / TOK, 256, 0, stream>>>(x, mask, W1, b1, W2, b2, Wc, bc,
                                          Wb1, bb1, Wb2, bb2, signal, e,
                                          hist16, merged, bounds);
  k_select<<<B_, 1024, 0, stream>>>(signal, hist16, starts, nlast);
  k_merge<<<BL_ / 4, 256, 0, stream>>>(x, mask, e, starts, nlast, merged, bounds);
}